// Round 6
// baseline (390.681 us; speedup 1.0000x reference)
//
#include <hip/hip_runtime.h>
#include <hip/hip_bf16.h>

typedef __bf16 bf16x8 __attribute__((ext_vector_type(8)));
typedef float  f32x4  __attribute__((ext_vector_type(4)));

#define DEV static __device__ __forceinline__

DEV float bf2f(ushort u) { unsigned x = ((unsigned)u) << 16; return __uint_as_float(x); }
DEV ushort f2bf(float f) {
    unsigned u = __float_as_uint(f);
    unsigned r = (u + 0x7FFFu + ((u >> 16) & 1u)) >> 16;  // RNE
    return (ushort)r;
}

typedef __attribute__((address_space(1))) const unsigned int gu32;
typedef __attribute__((address_space(3))) unsigned int lu32;
DEV void gload16(const ushort* g, ushort* l) {
    __builtin_amdgcn_global_load_lds((gu32*)g, (lu32*)l, 16, 0, 0);
}

// ---------------- fp32 -> bf16 weight conversion (one-time, tiny) ----------------
__global__ __launch_bounds__(256) void f2bf_kernel(
    const float* __restrict__ src, ushort* __restrict__ dst)
{
    int i = (blockIdx.x * 256 + threadIdx.x) * 4;
    float4 v = *(const float4*)(src + i);
    ushort4 o;
    o.x = f2bf(v.x); o.y = f2bf(v.y); o.z = f2bf(v.z); o.w = f2bf(v.w);
    *(ushort4*)(dst + i) = o;
}

// ---------------- attn-PE weight transpose: [256][9] fp32 -> [9][256] bf16 ----------------
__global__ __launch_bounds__(256) void pe_prep_kernel(
    const float* __restrict__ apw, ushort* __restrict__ wt)
{
    int i = blockIdx.x * 256 + threadIdx.x;
    if (i < 9 * 256) {
        int tap = i >> 8, c = i & 255;
        wt[i] = f2bf(apw[c * 9 + tap]);
    }
}

// ---------------- box filter: B[g][br][bc][256] bf16, br,bc in [0,65) ----------------
__global__ __launch_bounds__(256) void box_kernel(
    const float* __restrict__ x,   // [8][256][64][64] fp32
    ushort* __restrict__ B)        // [8][65][65][256] bf16
{
    int br = blockIdx.x % 65; int g = blockIdx.x / 65;
    const float* xg = x + (size_t)g * 256 * 4096;
    ushort* Bg = B + (size_t)g * 65 * 65 * 256;
    const int r0 = max(br - 1, 0) * 64;
    const int r1 = min(br, 63) * 64;
    __shared__ float s[128][65];
    const int wl = threadIdx.x & 63, cq = threadIdx.x >> 6;   // load mapping
    const int c2 = threadIdx.x & 127, bh = threadIdx.x >> 7;  // store mapping
    for (int half = 0; half < 2; ++half) {
#pragma unroll 4
        for (int it = 0; it < 32; ++it) {
            int cl_ = it * 4 + cq;
            const float* xp = xg + (size_t)(half * 128 + cl_) * 4096;
            s[cl_][wl] = xp[r0 + wl] + xp[r1 + wl];
        }
        __syncthreads();
        for (int bc = bh; bc < 65; bc += 2) {
            float v = 0.25f * (s[c2][max(bc - 1, 0)] + s[c2][min(bc, 63)]);
            Bg[((size_t)br * 65 + bc) * 256 + half * 128 + c2] = f2bf(v);
        }
        __syncthreads();
    }
}

// ---------------- pool gather + depthwise 3x3 + residual ----------------
template<int K, int L>
__global__ __launch_bounds__(256) void pool_kernel(
    const ushort* __restrict__ B,   // [8][65][65][256] bf16
    const float* __restrict__ w9,   // [256][9] fp32
    const float* __restrict__ bias, // [256] fp32
    ushort* __restrict__ y)         // bf16 out
{
    constexpr int HF = K / 2;
    const int pk = blockIdx.x;
    const int lw = pk % L; int t = pk / L; const int lh = t % L; const int g = t / L;
    const int c = threadIdx.x;
    const ushort* Bg = B + (size_t)g * 65 * 65 * 256 + c;
    float pool[K][K];
#pragma unroll
    for (int p = 0; p < K; ++p) {
        const int br = lh * 4 + p + (p >= HF ? 1 : 0);
#pragma unroll
        for (int q = 0; q < K; ++q) {
            const int bc = lw * 4 + q + (q >= HF ? 1 : 0);
            pool[p][q] = bf2f(Bg[((size_t)br * 65 + bc) * 256]);
        }
    }
    float wv[9];
#pragma unroll
    for (int i = 0; i < 9; ++i) wv[i] = w9[c * 9 + i];
    const float bv = bias[c];
    ushort* yp = y + (size_t)pk * (K * K) * 256 + c;
#pragma unroll
    for (int p = 0; p < K; ++p) {
#pragma unroll
        for (int q = 0; q < K; ++q) {
            float a = pool[p][q] + bv;   // residual + conv bias
#pragma unroll
            for (int dp = -1; dp <= 1; ++dp) {
#pragma unroll
                for (int dq = -1; dq <= 1; ++dq) {
                    int pp = p + dp, qq = q + dq;
                    if (pp >= 0 && pp < K && qq >= 0 && qq < K)
                        a += wv[(dp + 1) * 3 + (dq + 1)] * pool[pp][qq];
                }
            }
            yp[(p * K + q) * 256] = f2bf(a);
        }
    }
}

// ---------------- GEMM 128x128 tiles (m97 structure): global_load_lds staging,
// linear LDS dest + inverse-swizzled global source + swizzled ds_read_b128.
template<int OC, int EPI, int K, int L, int RT>
__global__ __launch_bounds__(256) void gemm_kernel(
    const ushort* __restrict__ act,  // [rows][256] bf16
    const ushort* __restrict__ w,    // [OC][256]  bf16
    const float* __restrict__ bias,  // [OC] fp32
    ushort* __restrict__ out_bf)
{
    __shared__ __attribute__((aligned(16))) ushort As[128][32];
    __shared__ __attribute__((aligned(16))) ushort Ws[128][32];
    constexpr int NT = OC / 128;
    const int id  = blockIdx.x;
    const int xc  = id & 7;                 // XCD-aware row-tile swizzle
    const int ctb = (id >> 3) % NT;
    const int tt  = id / (8 * NT);
    const int rowt = tt * 8 + xc;
    if (rowt >= RT) return;
    const int tid  = threadIdx.x;
    const int n0   = rowt * 128;
    const int ch0  = ctb * 128;
    const int wv   = tid >> 6, lane = tid & 63;
    const int l15  = lane & 15, quad = lane >> 4;
    const int wm   = wv >> 1, wn = wv & 1;   // 2x2 wave grid, 64x64 out per wave

    const int qlog = (lane & 3) ^ ((lane >> 3) & 3);
    const size_t soff = (size_t)(lane >> 2) * 256 + (size_t)qlog * 8;
    const ushort* aS0 = act + ((size_t)n0 + wv * 32) * 256 + soff;
    const ushort* wS0 = w   + ((size_t)ch0 + wv * 32) * 256 + soff;
    const ushort* aS1 = aS0 + 16 * 256;
    const ushort* wS1 = wS0 + 16 * 256;
    ushort* aD0 = &As[wv * 32][0];           // wave-uniform LDS bases
    ushort* wD0 = &Ws[wv * 32][0];
    ushort* aD1 = aD0 + 16 * 32;
    ushort* wD1 = wD0 + 16 * 32;

    const int rcol = (quad ^ ((l15 >> 1) & 3)) * 8;  // swizzled read column
    f32x4 acc[4][4] = {};
    for (int k0 = 0; k0 < 256; k0 += 32) {
        gload16(aS0 + k0, aD0);
        gload16(aS1 + k0, aD1);
        gload16(wS0 + k0, wD0);
        gload16(wS1 + k0, wD1);
        __syncthreads();                     // drains vmcnt before barrier
        bf16x8 af[4], bw[4];
#pragma unroll
        for (int t = 0; t < 4; ++t) {
            af[t] = *(const bf16x8*)&As[wm * 64 + t * 16 + l15][rcol];
            bw[t] = *(const bf16x8*)&Ws[wn * 64 + t * 16 + l15][rcol];
        }
#pragma unroll
        for (int mt = 0; mt < 4; ++mt)
#pragma unroll
            for (int nt = 0; nt < 4; ++nt)
                acc[mt][nt] = __builtin_amdgcn_mfma_f32_16x16x32_bf16(af[mt], bw[nt], acc[mt][nt], 0, 0, 0);
        __syncthreads();
    }

    float bv[4];
#pragma unroll
    for (int nt = 0; nt < 4; ++nt) bv[nt] = bias[ch0 + wn * 64 + nt * 16 + l15];
#pragma unroll
    for (int mt = 0; mt < 4; ++mt) {
#pragma unroll
        for (int r = 0; r < 4; ++r) {
            const int n = n0 + wm * 64 + mt * 16 + quad * 4 + r;
            if (EPI == 0) {
                ushort* dst = out_bf + (size_t)n * OC + ch0 + wn * 64;
#pragma unroll
                for (int nt = 0; nt < 4; ++nt)
                    dst[nt * 16 + l15] = f2bf(acc[mt][nt][r] + bv[nt]);
            } else {
                constexpr int K2 = K * K;
                constexpr int LL = L * L;
                const int b_g   = n >> (K == 8 ? 6 : 4);
                const int pq    = n & (K2 - 1);
                const int gl    = b_g / LL;
                const int b_loc = b_g - gl * LL;
                const size_t base = (size_t)gl * (256 * K2 * LL) + (size_t)b_loc * 256 * K2 + pq;
#pragma unroll
                for (int nt = 0; nt < 4; ++nt) {
                    const int ch = ch0 + wn * 64 + nt * 16 + l15;
                    out_bf[base + (size_t)ch * K2] = f2bf(acc[mt][nt][r] + bv[nt]);
                }
            }
        }
    }
}

// ---------------- MFMA attention for K=8 (NSP=64): block = 1 patch x 1 head, 128 thr.
// v3: channel-per-lane PE (b128 token-row reads from Vt), PE^T staging, 2 barriers,
// per-wave-disjoint LDS ownership. LDS 19.8KB -> 8 blocks/CU.
__global__ __launch_bounds__(128, 4) void attn8_mfma_kernel(
    const ushort* __restrict__ qkv,  // [patches*64][512] bf16
    const ushort* __restrict__ wt,   // [9][256] bf16 (transposed attn-PE weights)
    const float* __restrict__ pe_b,  // [256] fp32
    ushort* __restrict__ o_out)      // [patches*64][256] bf16
{
    constexpr float SCALE = 0.17677669529663687f;  // 32^-0.5
    __shared__ __attribute__((aligned(16))) ushort PB[64][72];  // PE^T[d][n] -> P[n][m] -> O[n][d]
    __shared__ __attribute__((aligned(16))) ushort Vt[64][72];  // V^T (d-major)
    __shared__ __attribute__((aligned(16))) ushort wsh[9][64];  // dwconv w for this head
    __shared__ float bsh[64];
    const int tid  = threadIdx.x;
    const int lane = tid & 63;
    const int ww   = tid >> 6;           // wave 0/1
    const int b    = blockIdx.x >> 2;    // patch
    const int h    = blockIdx.x & 3;     // head
    const int cbase = h * 64;
    const int l15  = lane & 15, quad = lane >> 4;
    const ushort* base = qkv + (size_t)b * 64 * 512 + h * 128;

    // ---- per-wave stage of dwconv weights + bias (own 32-channel half; intra-wave use only)
    if (lane < 36) {
        int tap = lane >> 2, c8 = (lane & 3) * 8;
        *(uint4*)&wsh[tap][ww * 32 + c8] = *(const uint4*)&wt[tap * 256 + cbase + ww * 32 + c8];
    }
    if (lane < 32) bsh[ww * 32 + lane] = pe_b[cbase + ww * 32 + lane];

    // ---- stage V^T: wave ww owns d rows [ww*32, ww*32+32), token m = lane
    {
        const int m = lane;
        const ushort* vsrc = base + (size_t)m * 512 + 64 + ww * 32;
        const int d0 = ww * 32;
#pragma unroll
        for (int t = 0; t < 4; ++t) {
            uint4 vv = *(const uint4*)(vsrc + t * 8);
            unsigned u[4] = {vv.x, vv.y, vv.z, vv.w};
#pragma unroll
            for (int e = 0; e < 4; ++e) {
                Vt[d0 + t * 8 + e * 2][m]     = (ushort)(u[e] & 0xFFFF);
                Vt[d0 + t * 8 + e * 2 + 1][m] = (ushort)(u[e] >> 16);
            }
        }
    }

    // ---- Q fragments + QK^T (registers/global only)
    bf16x8 fq[2];
#pragma unroll
    for (int s = 0; s < 2; ++s) {
        int n = (ww + 2 * s) * 16 + l15;
        fq[s] = *(const bf16x8*)(base + (size_t)n * 512 + quad * 8);
    }
    f32x4 S[2][4];
#pragma unroll
    for (int mt = 0; mt < 4; ++mt) {
        int m = mt * 16 + l15;
        bf16x8 fk = *(const bf16x8*)(base + (size_t)m * 512 + 32 + quad * 8);
#pragma unroll
        for (int s = 0; s < 2; ++s) {
            f32x4 z = {0.f, 0.f, 0.f, 0.f};
            S[s][mt] = __builtin_amdgcn_mfma_f32_16x16x32_bf16(fq[s], fk, z, 0, 0, 0);
        }
    }

    // ---- PE dwconv, channel-per-lane: thread -> (d = ww*32+(lane&31), rows p)
    // Reads own wave's Vt rows (intra-wave in-order LDS: no barrier needed).
    {
        const int d   = ww * 32 + (lane & 31);
        const int pb4 = (lane >> 5) * 4;
        float wreg[9];
#pragma unroll
        for (int i = 0; i < 9; ++i) wreg[i] = bf2f(wsh[i][d]);
        const float bias0 = bsh[d];
#pragma unroll
        for (int it = 0; it < 4; ++it) {
            const int p = pb4 + it;
            float pe[8];
#pragma unroll
            for (int q = 0; q < 8; ++q) pe[q] = bias0;
#pragma unroll
            for (int dpi = 0; dpi < 3; ++dpi) {
                const int pp = p + dpi - 1;
                if (pp >= 0 && pp < 8) {
                    bf16x8 v8 = *(const bf16x8*)&Vt[d][pp * 8];
                    float v[8];
#pragma unroll
                    for (int e = 0; e < 8; ++e) v[e] = (float)v8[e];
                    const float w0 = wreg[dpi * 3], w1 = wreg[dpi * 3 + 1], w2 = wreg[dpi * 3 + 2];
                    pe[0] += w1 * v[0] + w2 * v[1];
#pragma unroll
                    for (int q = 1; q < 7; ++q) pe[q] += w0 * v[q - 1] + w1 * v[q] + w2 * v[q + 1];
                    pe[7] += w0 * v[6] + w1 * v[7];
                }
            }
            ushort pk[8];
#pragma unroll
            for (int e = 0; e < 8; ++e) pk[e] = f2bf(pe[e]);
            *(uint4*)&PB[d][p * 8] = *(const uint4*)pk;   // PE^T: row d, tokens p*8..+8
        }
    }
    __syncthreads();   // barrier 1: Vt + PE^T visible to both waves

    // ---- O init from PE^T: O[s][dt][r] = PE[n][d], b64 reads (4 consecutive n)
    f32x4 O[2][4];
#pragma unroll
    for (int s = 0; s < 2; ++s)
#pragma unroll
        for (int dt = 0; dt < 4; ++dt) {
            ushort4 t4 = *(const ushort4*)&PB[dt * 16 + l15][(ww + 2 * s) * 16 + quad * 4];
            O[s][dt][0] = bf2f(t4.x);
            O[s][dt][1] = bf2f(t4.y);
            O[s][dt][2] = bf2f(t4.z);
            O[s][dt][3] = bf2f(t4.w);
        }

    // ---- softmax (wave-parallel, registers)
#pragma unroll
    for (int s = 0; s < 2; ++s) {
#pragma unroll
        for (int r = 0; r < 4; ++r) {
            float mx = -1e30f;
#pragma unroll
            for (int mt = 0; mt < 4; ++mt) { S[s][mt][r] *= SCALE; mx = fmaxf(mx, S[s][mt][r]); }
            mx = fmaxf(mx, __shfl_xor(mx, 1));
            mx = fmaxf(mx, __shfl_xor(mx, 2));
            mx = fmaxf(mx, __shfl_xor(mx, 4));
            mx = fmaxf(mx, __shfl_xor(mx, 8));
            float sum = 0.f;
#pragma unroll
            for (int mt = 0; mt < 4; ++mt) { float e = __expf(S[s][mt][r] - mx); S[s][mt][r] = e; sum += e; }
            sum += __shfl_xor(sum, 1);
            sum += __shfl_xor(sum, 2);
            sum += __shfl_xor(sum, 4);
            sum += __shfl_xor(sum, 8);
            float inv = 1.f / sum;
#pragma unroll
            for (int mt = 0; mt < 4; ++mt) S[s][mt][r] *= inv;
        }
    }
    __syncthreads();   // barrier 2: all PE^T reads complete before P overwrites PB

    // ---- P -> PB n-major. Wave ww writes only rows {ww*16..+16, (ww+2)*16..+16}:
    // disjoint per wave; PV below reads only own-wave rows -> no barrier needed.
#pragma unroll
    for (int s = 0; s < 2; ++s)
#pragma unroll
        for (int r = 0; r < 4; ++r) {
            int n = (ww + 2 * s) * 16 + quad * 4 + r;
#pragma unroll
            for (int mt = 0; mt < 4; ++mt)
                PB[n][mt * 16 + l15] = f2bf(S[s][mt][r]);
        }

    // ---- PV (fp from own-wave P rows; fv from Vt, unchanged since barrier 1)
#pragma unroll
    for (int ks = 0; ks < 2; ++ks) {
        bf16x8 fp[2], fv[4];
#pragma unroll
        for (int s = 0; s < 2; ++s)
            fp[s] = *(const bf16x8*)&PB[(ww + 2 * s) * 16 + l15][ks * 32 + quad * 8];
#pragma unroll
        for (int dt = 0; dt < 4; ++dt)
            fv[dt] = *(const bf16x8*)&Vt[dt * 16 + l15][ks * 32 + quad * 8];
#pragma unroll
        for (int s = 0; s < 2; ++s)
#pragma unroll
            for (int dt = 0; dt < 4; ++dt)
                O[s][dt] = __builtin_amdgcn_mfma_f32_16x16x32_bf16(fp[s], fv[dt], O[s][dt], 0, 0, 0);
    }

    // ---- O -> own-wave PB rows, then per-wave coalesced copy-out (intra-wave only)
#pragma unroll
    for (int s = 0; s < 2; ++s)
#pragma unroll
        for (int r = 0; r < 4; ++r) {
            int n = (ww + 2 * s) * 16 + quad * 4 + r;
#pragma unroll
            for (int dt = 0; dt < 4; ++dt)
                PB[n][dt * 16 + l15] = f2bf(O[s][dt][r]);
        }
#pragma unroll
    for (int it = 0; it < 4; ++it) {
        int cidx = it * 64 + lane;               // 256 chunk-copies per wave
        int rl = cidx >> 3, c8 = (cidx & 7) * 8;
        int row = ww * 16 + (rl & 15) + (rl >> 4) * 32;  // own-wave rows only
        uint4 v = *(const uint4*)&PB[row][c8];
        *(uint4*)(o_out + (size_t)(b * 64 + row) * 256 + cbase + c8) = v;
    }
}

// ---------------- MFMA attention for K=4 (NSP=16): block = 1 patch, wave = 1 head.
// One 16x16x32 MFMA for QK^T; PV via zero-padded (K=32, m>=16 zero) MFMAs.
// Waves fully independent after one weights barrier.
__global__ __launch_bounds__(256) void attn4_mfma_kernel(
    const ushort* __restrict__ qkv,  // [2048*16][512] bf16
    const ushort* __restrict__ wt,   // [9][256] bf16
    const float* __restrict__ pe_b,  // [256] fp32
    ushort* __restrict__ o_out)      // [2048*16][256] bf16
{
    constexpr float SCALE = 0.17677669529663687f;  // 32^-0.5
    __shared__ __attribute__((aligned(16))) ushort wsh[9][256];   // dwconv weights, all heads
    __shared__ float bsh[256];
    __shared__ __attribute__((aligned(16))) ushort Vt4[4][64][32]; // [wave][d][m swz], m>=16 zero
    __shared__ __attribute__((aligned(16))) ushort VP[4][16][64];  // V rows -> PE -> O (per wave)
    __shared__ __attribute__((aligned(16))) ushort Pm[4][16][32];  // P[n][m swz], m>=16 zero
    const int tid  = threadIdx.x;
    const int lane = tid & 63;
    const int w    = tid >> 6;       // wave = head
    const int b    = blockIdx.x;     // patch
    const int h    = w;
    const int cbase = h * 64;
    const int l15  = lane & 15, quad = lane >> 4;
    const ushort* base = qkv + (size_t)b * 16 * 512 + h * 128;

    // ---- cooperative stage of dwconv weights + bias (only cross-wave dependency)
    for (int i = tid; i < 9 * 32; i += 256) {
        int tap = i >> 5, c8 = (i & 31) * 8;
        *(uint4*)&wsh[tap][c8] = *(const uint4*)&wt[tap * 256 + c8];
    }
    bsh[tid] = pe_b[tid];
    __syncthreads();

    // ---- zero Vt4 (m>=16 rows must be 0 for the padded MFMA) and Pm
    {
        uint4 z = {0u, 0u, 0u, 0u};
#pragma unroll
        for (int t = 0; t < 4; ++t)
            *(uint4*)&Vt4[w][t * 16 + (lane >> 2)][(lane & 3) * 8] = z;
        *(uint4*)&Pm[w][lane >> 2][(lane & 3) * 8] = z;
    }

    // ---- stage V: lane -> (token m = lane&15, d-block = lane>>4)
    {
        const int m = lane & 15, dblk = lane >> 4;
        const ushort* vsrc = base + (size_t)m * 512 + 64 + dblk * 16;
        uint4 v0 = *(const uint4*)(vsrc);
        uint4 v1 = *(const uint4*)(vsrc + 8);
        *(uint4*)&VP[w][m][dblk * 16]     = v0;   // row-major copy (PE source)
        *(uint4*)&VP[w][m][dblk * 16 + 8] = v1;
        ushort us[16];
        *(uint4*)&us[0] = v0; *(uint4*)&us[8] = v1;
        const int mb = m >> 3, m7 = m & 7;
#pragma unroll
        for (int e = 0; e < 16; ++e) {
            int d = dblk * 16 + e;
            Vt4[w][d][((mb ^ (d & 3)) << 3) + m7] = us[e];  // d-major, col-swizzled
        }
    }

    // ---- QK^T: one 16x16x32 MFMA
    bf16x8 fq = *(const bf16x8*)(base + (size_t)l15 * 512 + quad * 8);
    bf16x8 fk = *(const bf16x8*)(base + (size_t)l15 * 512 + 32 + quad * 8);
    f32x4 z4 = {0.f, 0.f, 0.f, 0.f};
    f32x4 S = __builtin_amdgcn_mfma_f32_16x16x32_bf16(fq, fk, z4, 0, 0, 0);
    // lane holds S[n=quad*4+r][m=l15]

    // ---- softmax over m (across l15 within 16-lane group), wave-parallel
    float p[4];
#pragma unroll
    for (int r = 0; r < 4; ++r) {
        float v = S[r] * SCALE;
        float mx = v;
        mx = fmaxf(mx, __shfl_xor(mx, 1));
        mx = fmaxf(mx, __shfl_xor(mx, 2));
        mx = fmaxf(mx, __shfl_xor(mx, 4));
        mx = fmaxf(mx, __shfl_xor(mx, 8));
        float e = __expf(v - mx);
        float sum = e;
        sum += __shfl_xor(sum, 1);
        sum += __shfl_xor(sum, 2);
        sum += __shfl_xor(sum, 4);
        sum += __shfl_xor(sum, 8);
        p[r] = e / sum;
    }
    // ---- P -> Pm (swizzled cols; logical m>=16 stays zero)
#pragma unroll
    for (int r = 0; r < 4; ++r) {
        int n = quad * 4 + r;
        Pm[w][n][(((l15 >> 3) ^ (n & 3)) << 3) + (l15 & 7)] = f2bf(p[r]);
    }

    // ---- PE dwconv3x3 over V (from VP rows), 2 items/lane: (n=lane&15, ch, ch+4)
    float pe[2][8];
    const int n_ = lane & 15;
    const int pp0 = n_ >> 2, qq0 = n_ & 3;
#pragma unroll
    for (int it = 0; it < 2; ++it) {
        int ch = (lane >> 4) + it * 4;
#pragma unroll
        for (int e = 0; e < 8; ++e) pe[it][e] = bsh[cbase + ch * 8 + e];
    }
#pragma unroll
    for (int tap = 0; tap < 9; ++tap) {
        const int dp = tap / 3 - 1, dq = tap % 3 - 1;
        const int pp = pp0 + dp, qq = qq0 + dq;
        if (pp >= 0 && pp < 4 && qq >= 0 && qq < 4) {
            const int mm = pp * 4 + qq;
#pragma unroll
            for (int it = 0; it < 2; ++it) {
                int ch = (lane >> 4) + it * 4;
                uint4 wv4 = *(const uint4*)&wsh[tap][cbase + ch * 8];
                uint4 vv  = *(const uint4*)&VP[w][mm][ch * 8];
                unsigned uw[4] = {wv4.x, wv4.y, wv4.z, wv4.w};
                unsigned uv[4] = {vv.x, vv.y, vv.z, vv.w};
#pragma unroll
                for (int e2 = 0; e2 < 4; ++e2) {
                    float wlo = __uint_as_float(uw[e2] << 16);
                    float whi = __uint_as_float(uw[e2] & 0xFFFF0000u);
                    float vlo = __uint_as_float(uv[e2] << 16);
                    float vhi = __uint_as_float(uv[e2] & 0xFFFF0000u);
                    pe[it][2 * e2]     += wlo * vlo;
                    pe[it][2 * e2 + 1] += whi * vhi;
                }
            }
        }
    }
    // store PE into VP (all taps read before any store: same-wave program order)
#pragma unroll
    for (int it = 0; it < 2; ++it) {
        int ch = (lane >> 4) + it * 4;
        ushort pk[8];
#pragma unroll
        for (int e = 0; e < 8; ++e) pk[e] = f2bf(pe[it][e]);
        *(uint4*)&VP[w][n_][ch * 8] = *(const uint4*)pk;
    }

    // ---- O init from PE: O[n=quad*4+r][d=dt*16+l15]
    f32x4 O[4];
#pragma unroll
    for (int dt = 0; dt < 4; ++dt)
#pragma unroll
        for (int r = 0; r < 4; ++r)
            O[dt][r] = bf2f(VP[w][quad * 4 + r][dt * 16 + l15]);

    // ---- PV: 4 zero-padded 16x16x32 MFMAs
    bf16x8 fp = *(const bf16x8*)&Pm[w][l15][((quad ^ (l15 & 3)) << 3)];
#pragma unroll
    for (int dt = 0; dt < 4; ++dt) {
        bf16x8 fv = *(const bf16x8*)&Vt4[w][dt * 16 + l15][((quad ^ (l15 & 3)) << 3)];
        O[dt] = __builtin_amdgcn_mfma_f32_16x16x32_bf16(fp, fv, O[dt], 0, 0, 0);
    }

    // ---- O -> VP, then coalesced copy-out (16 rows x 128B)
#pragma unroll
    for (int dt = 0; dt < 4; ++dt)
#pragma unroll
        for (int r = 0; r < 4; ++r)
            VP[w][quad * 4 + r][dt * 16 + l15] = f2bf(O[dt][r]);

#pragma unroll
    for (int j = 0; j < 2; ++j) {
        int idx = j * 64 + lane;            // 0..127
        int row = idx >> 3, c8 = (idx & 7) * 8;
        uint4 v = *(const uint4*)&VP[w][row][c8];
        *(uint4*)(o_out + (size_t)(b * 16 + row) * 256 + cbase + c8) = v;
    }
}

// ---------------- final: out = (x + fold8(s8) + fold4(s4)) / 3 ----------------
__global__ __launch_bounds__(256) void final_kernel(
    const float* __restrict__ x,
    const ushort* __restrict__ s8,
    const ushort* __restrict__ s4,
    float* __restrict__ out)
{
    const int c2 = blockIdx.x & 255;
    const int g  = blockIdx.x >> 8;
    const ushort* s8g = s8 + (size_t)g * (256 * 64 * 225);
    const ushort* s4g = s4 + (size_t)g * (256 * 16 * 256);
    const float third = 1.f / 3.f;
#pragma unroll 2
    for (int it = 0; it < 16; ++it) {
        int pix = it * 256 + threadIdx.x;       // h*64 + w
        int h = pix >> 6, w = pix & 63;
        int f4 = ((((c2 * 4 + (h & 3)) * 4 + (w & 3)) * 16 + (h >> 2)) * 16) + (w >> 2);
        float v4 = bf2f(s4g[f4]);
        int lh_lo = (h >= 8) ? ((h - 4) >> 2) : 0, lh_hi = min(14, h >> 2);
        int lw_lo = (w >= 8) ? ((w - 4) >> 2) : 0, lw_hi = min(14, w >> 2);
        float v8 = 0.f;
        for (int lh2 = lh_lo; lh2 <= lh_hi; ++lh2) {
            int p2 = h - lh2 * 4;
            for (int lw2 = lw_lo; lw2 <= lw_hi; ++lw2) {
                int q2 = w - lw2 * 4;
                int f8 = (((c2 * 8 + p2) * 8 + q2) * 15 + lh2) * 15 + lw2;
                v8 += bf2f(s8g[f8]);
            }
        }
        float inv = 1.f / (float)((lh_hi - lh_lo + 1) * (lw_hi - lw_lo + 1));
        size_t off = ((size_t)(g * 256 + c2)) * 4096 + pix;
        out[off] = (x[off] + v8 * inv + v4) * third;
    }
}

extern "C" void kernel_launch(void* const* d_in, const int* in_sizes, int n_in,
                              void* d_out, int out_size, void* d_ws, size_t ws_size,
                              hipStream_t stream)
{
    const float* x      = (const float*)d_in[0];
    const float* qkv_w  = (const float*)d_in[1];
    const float* qkv_b  = (const float*)d_in[2];
    const float* proj_w = (const float*)d_in[3];
    const float* proj_b = (const float*)d_in[4];
    const float* apw    = (const float*)d_in[5];
    const float* apb    = (const float*)d_in[6];
    const float* dpw    = (const float*)d_in[7];
    const float* dpb    = (const float*)d_in[8];
    float* out = (float*)d_out;

    // Workspace: s8 59 + s4 16.8 + y 29.5 + q 59 + w 0.4 + B(bf16) 17.3 = 182.1 MB
    const size_t S8_B = 8ull * 225 * 256 * 64 * 2;
    const size_t S4_B = 8ull * 256 * 256 * 16 * 2;
    const size_t Y_B  = 4ull * 14400 * 256 * 2;
    const size_t Q_B  = 4ull * 14400 * 512 * 2;
    const size_t W_B  = (512ull * 256 + 256ull * 256 + 9ull * 256) * 2;
    const size_t B_B  = 8ull * 65 * 65 * 256 * 2;
    if (ws_size < S8_B + S4_B + Y_B + Q_B + W_B + B_B) {
        hipMemsetAsync(d_out, 0x46, 4, stream);  // finite sentinel: ws too small
        return;
    }
    ushort* s8    = (ushort*)d_ws;
    ushort* s4    = s8 + S8_B / 2;
    ushort* ybuf  = s4 + S4_B / 2;
    ushort* qbuf  = ybuf + Y_B / 2;
    ushort* qw_bf = qbuf + Q_B / 2;
    ushort* pw_bf = qw_bf + 512 * 256;
    ushort* wt    = pw_bf + 256 * 256;
    ushort* Bbuf  = (ushort*)((char*)d_ws + S8_B + S4_B + Y_B + Q_B + W_B);

    f2bf_kernel<<<128, 256, 0, stream>>>(qkv_w, qw_bf);
    f2bf_kernel<<<64, 256, 0, stream>>>(proj_w, pw_bf);
    pe_prep_kernel<<<9, 256, 0, stream>>>(apw, wt);
    box_kernel<<<8 * 65, 256, 0, stream>>>(x, Bbuf);   // all 8 images, once

    // K=8 chain (L=15), two halves of 4 images: 4*14400 = 57600 rows = 450 tiles of 128
    for (int hf = 0; hf < 2; ++hf) {
        ushort* B_h = Bbuf + (size_t)hf * 4 * 65 * 65 * 256;
        ushort* s8_h = s8 + (size_t)hf * 4 * 225 * 256 * 64;
        pool_kernel<8, 15><<<4 * 225, 256, 0, stream>>>(B_h, dpw, dpb, ybuf);
        gemm_kernel<512, 0, 8, 15, 450><<<57 * 8 * 4, 256, 0, stream>>>(ybuf, qw_bf, qkv_b, qbuf);
        attn8_mfma_kernel<<<900 * 4, 128, 0, stream>>>(qbuf, wt, apb, ybuf);
        gemm_kernel<256, 1, 8, 15, 450><<<57 * 8 * 2, 256, 0, stream>>>(ybuf, pw_bf, proj_b, s8_h);
    }
    // K=4 chain (L=16), all 8 images: 8*4096 = 32768 rows = 256 tiles of 128
    pool_kernel<4, 16><<<8 * 256, 256, 0, stream>>>(Bbuf, dpw, dpb, ybuf);
    gemm_kernel<512, 0, 4, 16, 256><<<32 * 8 * 4, 256, 0, stream>>>(ybuf, qw_bf, qkv_b, qbuf);
    attn4_mfma_kernel<<<2048, 256, 0, stream>>>(qbuf, wt, apb, ybuf);
    gemm_kernel<256, 1, 4, 16, 256><<<32 * 8 * 2, 256, 0, stream>>>(ybuf, pw_bf, proj_b, s4);

    final_kernel<<<2048, 256, 0, stream>>>(x, s8, s4, out);
}

// Round 7
// 369.083 us; speedup vs baseline: 1.0585x; 1.0585x over previous
//
#include <hip/hip_runtime.h>
#include <hip/hip_bf16.h>

typedef __bf16 bf16x8 __attribute__((ext_vector_type(8)));
typedef float  f32x4  __attribute__((ext_vector_type(4)));

#define DEV static __device__ __forceinline__

DEV float bf2f(ushort u) { unsigned x = ((unsigned)u) << 16; return __uint_as_float(x); }
DEV ushort f2bf(float f) {
    unsigned u = __float_as_uint(f);
    unsigned r = (u + 0x7FFFu + ((u >> 16) & 1u)) >> 16;  // RNE
    return (ushort)r;
}

typedef __attribute__((address_space(1))) const unsigned int gu32;
typedef __attribute__((address_space(3))) unsigned int lu32;
DEV void gload16(const ushort* g, ushort* l) {
    __builtin_amdgcn_global_load_lds((gu32*)g, (lu32*)l, 16, 0, 0);
}

// ---------------- fp32 -> bf16 weight conversion (one-time, tiny) ----------------
__global__ __launch_bounds__(256) void f2bf_kernel(
    const float* __restrict__ src, ushort* __restrict__ dst)
{
    int i = (blockIdx.x * 256 + threadIdx.x) * 4;
    float4 v = *(const float4*)(src + i);
    ushort4 o;
    o.x = f2bf(v.x); o.y = f2bf(v.y); o.z = f2bf(v.z); o.w = f2bf(v.w);
    *(ushort4*)(dst + i) = o;
}

// ---------------- attn-PE weight transpose: [256][9] fp32 -> [9][256] bf16 ----------------
__global__ __launch_bounds__(256) void pe_prep_kernel(
    const float* __restrict__ apw, ushort* __restrict__ wt)
{
    int i = blockIdx.x * 256 + threadIdx.x;
    if (i < 9 * 256) {
        int tap = i >> 8, c = i & 255;
        wt[i] = f2bf(apw[c * 9 + tap]);
    }
}

// ---------------- box filter: B[g][br][bc][256] bf16, br,bc in [0,65) ----------------
__global__ __launch_bounds__(256) void box_kernel(
    const float* __restrict__ x,   // [8][256][64][64] fp32
    ushort* __restrict__ B)        // [8][65][65][256] bf16
{
    int br = blockIdx.x % 65; int g = blockIdx.x / 65;
    const float* xg = x + (size_t)g * 256 * 4096;
    ushort* Bg = B + (size_t)g * 65 * 65 * 256;
    const int r0 = max(br - 1, 0) * 64;
    const int r1 = min(br, 63) * 64;
    __shared__ float s[128][65];
    const int wl = threadIdx.x & 63, cq = threadIdx.x >> 6;   // load mapping
    const int c2 = threadIdx.x & 127, bh = threadIdx.x >> 7;  // store mapping
    for (int half = 0; half < 2; ++half) {
#pragma unroll 4
        for (int it = 0; it < 32; ++it) {
            int cl_ = it * 4 + cq;
            const float* xp = xg + (size_t)(half * 128 + cl_) * 4096;
            s[cl_][wl] = xp[r0 + wl] + xp[r1 + wl];
        }
        __syncthreads();
        for (int bc = bh; bc < 65; bc += 2) {
            float v = 0.25f * (s[c2][max(bc - 1, 0)] + s[c2][min(bc, 63)]);
            Bg[((size_t)br * 65 + bc) * 256 + half * 128 + c2] = f2bf(v);
        }
        __syncthreads();
    }
}

// ---------------- pool gather + depthwise 3x3 + residual ----------------
template<int K, int L>
__global__ __launch_bounds__(256) void pool_kernel(
    const ushort* __restrict__ B,   // [8][65][65][256] bf16
    const float* __restrict__ w9,   // [256][9] fp32
    const float* __restrict__ bias, // [256] fp32
    ushort* __restrict__ y)         // bf16 out
{
    constexpr int HF = K / 2;
    const int pk = blockIdx.x;
    const int lw = pk % L; int t = pk / L; const int lh = t % L; const int g = t / L;
    const int c = threadIdx.x;
    const ushort* Bg = B + (size_t)g * 65 * 65 * 256 + c;
    float pool[K][K];
#pragma unroll
    for (int p = 0; p < K; ++p) {
        const int br = lh * 4 + p + (p >= HF ? 1 : 0);
#pragma unroll
        for (int q = 0; q < K; ++q) {
            const int bc = lw * 4 + q + (q >= HF ? 1 : 0);
            pool[p][q] = bf2f(Bg[((size_t)br * 65 + bc) * 256]);
        }
    }
    float wv[9];
#pragma unroll
    for (int i = 0; i < 9; ++i) wv[i] = w9[c * 9 + i];
    const float bv = bias[c];
    ushort* yp = y + (size_t)pk * (K * K) * 256 + c;
#pragma unroll
    for (int p = 0; p < K; ++p) {
#pragma unroll
        for (int q = 0; q < K; ++q) {
            float a = pool[p][q] + bv;   // residual + conv bias
#pragma unroll
            for (int dp = -1; dp <= 1; ++dp) {
#pragma unroll
                for (int dq = -1; dq <= 1; ++dq) {
                    int pp = p + dp, qq = q + dq;
                    if (pp >= 0 && pp < K && qq >= 0 && qq < K)
                        a += wv[(dp + 1) * 3 + (dq + 1)] * pool[pp][qq];
                }
            }
            yp[(p * K + q) * 256] = f2bf(a);
        }
    }
}

// ---------------- GEMM 128x128 tiles (m97 structure): global_load_lds staging,
// linear LDS dest + inverse-swizzled global source + swizzled ds_read_b128.
template<int OC, int EPI, int K, int L, int RT>
__global__ __launch_bounds__(256) void gemm_kernel(
    const ushort* __restrict__ act,  // [rows][256] bf16
    const ushort* __restrict__ w,    // [OC][256]  bf16
    const float* __restrict__ bias,  // [OC] fp32
    ushort* __restrict__ out_bf)
{
    __shared__ __attribute__((aligned(16))) ushort As[128][32];
    __shared__ __attribute__((aligned(16))) ushort Ws[128][32];
    constexpr int NT = OC / 128;
    const int id  = blockIdx.x;
    const int xc  = id & 7;                 // XCD-aware row-tile swizzle
    const int ctb = (id >> 3) % NT;
    const int tt  = id / (8 * NT);
    const int rowt = tt * 8 + xc;
    if (rowt >= RT) return;
    const int tid  = threadIdx.x;
    const int n0   = rowt * 128;
    const int ch0  = ctb * 128;
    const int wv   = tid >> 6, lane = tid & 63;
    const int l15  = lane & 15, quad = lane >> 4;
    const int wm   = wv >> 1, wn = wv & 1;   // 2x2 wave grid, 64x64 out per wave

    const int qlog = (lane & 3) ^ ((lane >> 3) & 3);
    const size_t soff = (size_t)(lane >> 2) * 256 + (size_t)qlog * 8;
    const ushort* aS0 = act + ((size_t)n0 + wv * 32) * 256 + soff;
    const ushort* wS0 = w   + ((size_t)ch0 + wv * 32) * 256 + soff;
    const ushort* aS1 = aS0 + 16 * 256;
    const ushort* wS1 = wS0 + 16 * 256;
    ushort* aD0 = &As[wv * 32][0];           // wave-uniform LDS bases
    ushort* wD0 = &Ws[wv * 32][0];
    ushort* aD1 = aD0 + 16 * 32;
    ushort* wD1 = wD0 + 16 * 32;

    const int rcol = (quad ^ ((l15 >> 1) & 3)) * 8;  // swizzled read column
    f32x4 acc[4][4] = {};
    for (int k0 = 0; k0 < 256; k0 += 32) {
        gload16(aS0 + k0, aD0);
        gload16(aS1 + k0, aD1);
        gload16(wS0 + k0, wD0);
        gload16(wS1 + k0, wD1);
        __syncthreads();                     // drains vmcnt before barrier
        bf16x8 af[4], bw[4];
#pragma unroll
        for (int t = 0; t < 4; ++t) {
            af[t] = *(const bf16x8*)&As[wm * 64 + t * 16 + l15][rcol];
            bw[t] = *(const bf16x8*)&Ws[wn * 64 + t * 16 + l15][rcol];
        }
#pragma unroll
        for (int mt = 0; mt < 4; ++mt)
#pragma unroll
            for (int nt = 0; nt < 4; ++nt)
                acc[mt][nt] = __builtin_amdgcn_mfma_f32_16x16x32_bf16(af[mt], bw[nt], acc[mt][nt], 0, 0, 0);
        __syncthreads();
    }

    float bv[4];
#pragma unroll
    for (int nt = 0; nt < 4; ++nt) bv[nt] = bias[ch0 + wn * 64 + nt * 16 + l15];
#pragma unroll
    for (int mt = 0; mt < 4; ++mt) {
#pragma unroll
        for (int r = 0; r < 4; ++r) {
            const int n = n0 + wm * 64 + mt * 16 + quad * 4 + r;
            if (EPI == 0) {
                ushort* dst = out_bf + (size_t)n * OC + ch0 + wn * 64;
#pragma unroll
                for (int nt = 0; nt < 4; ++nt)
                    dst[nt * 16 + l15] = f2bf(acc[mt][nt][r] + bv[nt]);
            } else {
                constexpr int K2 = K * K;
                constexpr int LL = L * L;
                const int b_g   = n >> (K == 8 ? 6 : 4);
                const int pq    = n & (K2 - 1);
                const int gl    = b_g / LL;
                const int b_loc = b_g - gl * LL;
                const size_t base = (size_t)gl * (256 * K2 * LL) + (size_t)b_loc * 256 * K2 + pq;
#pragma unroll
                for (int nt = 0; nt < 4; ++nt) {
                    const int ch = ch0 + wn * 64 + nt * 16 + l15;
                    out_bf[base + (size_t)ch * K2] = f2bf(acc[mt][nt][r] + bv[nt]);
                }
            }
        }
    }
}

// ---------------- MFMA attention for K=8 (NSP=64): block = 1 patch x 1 head, 128 thr.
// v3: channel-per-lane PE (b128 token-row reads from Vt), PE^T staging, 2 barriers,
// per-wave-disjoint LDS ownership. LDS 19.8KB -> 8 blocks/CU.
__global__ __launch_bounds__(128, 4) void attn8_mfma_kernel(
    const ushort* __restrict__ qkv,  // [patches*64][512] bf16
    const ushort* __restrict__ wt,   // [9][256] bf16 (transposed attn-PE weights)
    const float* __restrict__ pe_b,  // [256] fp32
    ushort* __restrict__ o_out)      // [patches*64][256] bf16
{
    constexpr float SCALE = 0.17677669529663687f;  // 32^-0.5
    __shared__ __attribute__((aligned(16))) ushort PB[64][72];  // PE^T[d][n] -> P[n][m] -> O[n][d]
    __shared__ __attribute__((aligned(16))) ushort Vt[64][72];  // V^T (d-major)
    __shared__ __attribute__((aligned(16))) ushort wsh[9][64];  // dwconv w for this head
    __shared__ float bsh[64];
    const int tid  = threadIdx.x;
    const int lane = tid & 63;
    const int ww   = tid >> 6;           // wave 0/1
    const int b    = blockIdx.x >> 2;    // patch
    const int h    = blockIdx.x & 3;     // head
    const int cbase = h * 64;
    const int l15  = lane & 15, quad = lane >> 4;
    const ushort* base = qkv + (size_t)b * 64 * 512 + h * 128;

    // ---- per-wave stage of dwconv weights + bias (own 32-channel half; intra-wave use only)
    if (lane < 36) {
        int tap = lane >> 2, c8 = (lane & 3) * 8;
        *(uint4*)&wsh[tap][ww * 32 + c8] = *(const uint4*)&wt[tap * 256 + cbase + ww * 32 + c8];
    }
    if (lane < 32) bsh[ww * 32 + lane] = pe_b[cbase + ww * 32 + lane];

    // ---- stage V^T: wave ww owns d rows [ww*32, ww*32+32), token m = lane
    {
        const int m = lane;
        const ushort* vsrc = base + (size_t)m * 512 + 64 + ww * 32;
        const int d0 = ww * 32;
#pragma unroll
        for (int t = 0; t < 4; ++t) {
            uint4 vv = *(const uint4*)(vsrc + t * 8);
            unsigned u[4] = {vv.x, vv.y, vv.z, vv.w};
#pragma unroll
            for (int e = 0; e < 4; ++e) {
                Vt[d0 + t * 8 + e * 2][m]     = (ushort)(u[e] & 0xFFFF);
                Vt[d0 + t * 8 + e * 2 + 1][m] = (ushort)(u[e] >> 16);
            }
        }
    }

    // ---- Q fragments + QK^T (registers/global only)
    bf16x8 fq[2];
#pragma unroll
    for (int s = 0; s < 2; ++s) {
        int n = (ww + 2 * s) * 16 + l15;
        fq[s] = *(const bf16x8*)(base + (size_t)n * 512 + quad * 8);
    }
    f32x4 S[2][4];
#pragma unroll
    for (int mt = 0; mt < 4; ++mt) {
        int m = mt * 16 + l15;
        bf16x8 fk = *(const bf16x8*)(base + (size_t)m * 512 + 32 + quad * 8);
#pragma unroll
        for (int s = 0; s < 2; ++s) {
            f32x4 z = {0.f, 0.f, 0.f, 0.f};
            S[s][mt] = __builtin_amdgcn_mfma_f32_16x16x32_bf16(fq[s], fk, z, 0, 0, 0);
        }
    }

    // ---- PE dwconv, channel-per-lane: thread -> (d = ww*32+(lane&31), rows p)
    // Reads own wave's Vt rows (intra-wave in-order LDS: no barrier needed).
    {
        const int d   = ww * 32 + (lane & 31);
        const int pb4 = (lane >> 5) * 4;
        float wreg[9];
#pragma unroll
        for (int i = 0; i < 9; ++i) wreg[i] = bf2f(wsh[i][d]);
        const float bias0 = bsh[d];
#pragma unroll
        for (int it = 0; it < 4; ++it) {
            const int p = pb4 + it;
            float pe[8];
#pragma unroll
            for (int q = 0; q < 8; ++q) pe[q] = bias0;
#pragma unroll
            for (int dpi = 0; dpi < 3; ++dpi) {
                const int pp = p + dpi - 1;
                if (pp >= 0 && pp < 8) {
                    bf16x8 v8 = *(const bf16x8*)&Vt[d][pp * 8];
                    float v[8];
#pragma unroll
                    for (int e = 0; e < 8; ++e) v[e] = (float)v8[e];
                    const float w0 = wreg[dpi * 3], w1 = wreg[dpi * 3 + 1], w2 = wreg[dpi * 3 + 2];
                    pe[0] += w1 * v[0] + w2 * v[1];
#pragma unroll
                    for (int q = 1; q < 7; ++q) pe[q] += w0 * v[q - 1] + w1 * v[q] + w2 * v[q + 1];
                    pe[7] += w0 * v[6] + w1 * v[7];
                }
            }
            ushort pk[8];
#pragma unroll
            for (int e = 0; e < 8; ++e) pk[e] = f2bf(pe[e]);
            *(uint4*)&PB[d][p * 8] = *(const uint4*)pk;   // PE^T: row d, tokens p*8..+8
        }
    }
    __syncthreads();   // barrier 1: Vt + PE^T visible to both waves

    // ---- O init from PE^T: O[s][dt][r] = PE[n][d], b64 reads (4 consecutive n)
    f32x4 O[2][4];
#pragma unroll
    for (int s = 0; s < 2; ++s)
#pragma unroll
        for (int dt = 0; dt < 4; ++dt) {
            ushort4 t4 = *(const ushort4*)&PB[dt * 16 + l15][(ww + 2 * s) * 16 + quad * 4];
            O[s][dt][0] = bf2f(t4.x);
            O[s][dt][1] = bf2f(t4.y);
            O[s][dt][2] = bf2f(t4.z);
            O[s][dt][3] = bf2f(t4.w);
        }

    // ---- softmax (wave-parallel, registers)
#pragma unroll
    for (int s = 0; s < 2; ++s) {
#pragma unroll
        for (int r = 0; r < 4; ++r) {
            float mx = -1e30f;
#pragma unroll
            for (int mt = 0; mt < 4; ++mt) { S[s][mt][r] *= SCALE; mx = fmaxf(mx, S[s][mt][r]); }
            mx = fmaxf(mx, __shfl_xor(mx, 1));
            mx = fmaxf(mx, __shfl_xor(mx, 2));
            mx = fmaxf(mx, __shfl_xor(mx, 4));
            mx = fmaxf(mx, __shfl_xor(mx, 8));
            float sum = 0.f;
#pragma unroll
            for (int mt = 0; mt < 4; ++mt) { float e = __expf(S[s][mt][r] - mx); S[s][mt][r] = e; sum += e; }
            sum += __shfl_xor(sum, 1);
            sum += __shfl_xor(sum, 2);
            sum += __shfl_xor(sum, 4);
            sum += __shfl_xor(sum, 8);
            float inv = 1.f / sum;
#pragma unroll
            for (int mt = 0; mt < 4; ++mt) S[s][mt][r] *= inv;
        }
    }
    __syncthreads();   // barrier 2: all PE^T reads complete before P overwrites PB

    // ---- P -> PB n-major. Wave ww writes only rows {ww*16..+16, (ww+2)*16..+16}:
    // disjoint per wave; PV below reads only own-wave rows -> no barrier needed.
#pragma unroll
    for (int s = 0; s < 2; ++s)
#pragma unroll
        for (int r = 0; r < 4; ++r) {
            int n = (ww + 2 * s) * 16 + quad * 4 + r;
#pragma unroll
            for (int mt = 0; mt < 4; ++mt)
                PB[n][mt * 16 + l15] = f2bf(S[s][mt][r]);
        }

    // ---- PV (fp from own-wave P rows; fv from Vt, unchanged since barrier 1)
#pragma unroll
    for (int ks = 0; ks < 2; ++ks) {
        bf16x8 fp[2], fv[4];
#pragma unroll
        for (int s = 0; s < 2; ++s)
            fp[s] = *(const bf16x8*)&PB[(ww + 2 * s) * 16 + l15][ks * 32 + quad * 8];
#pragma unroll
        for (int dt = 0; dt < 4; ++dt)
            fv[dt] = *(const bf16x8*)&Vt[dt * 16 + l15][ks * 32 + quad * 8];
#pragma unroll
        for (int s = 0; s < 2; ++s)
#pragma unroll
            for (int dt = 0; dt < 4; ++dt)
                O[s][dt] = __builtin_amdgcn_mfma_f32_16x16x32_bf16(fp[s], fv[dt], O[s][dt], 0, 0, 0);
    }

    // ---- O -> own-wave PB rows, then per-wave coalesced copy-out (intra-wave only)
#pragma unroll
    for (int s = 0; s < 2; ++s)
#pragma unroll
        for (int r = 0; r < 4; ++r) {
            int n = (ww + 2 * s) * 16 + quad * 4 + r;
#pragma unroll
            for (int dt = 0; dt < 4; ++dt)
                PB[n][dt * 16 + l15] = f2bf(O[s][dt][r]);
        }
#pragma unroll
    for (int it = 0; it < 4; ++it) {
        int cidx = it * 64 + lane;               // 256 chunk-copies per wave
        int rl = cidx >> 3, c8 = (cidx & 7) * 8;
        int row = ww * 16 + (rl & 15) + (rl >> 4) * 32;  // own-wave rows only
        uint4 v = *(const uint4*)&PB[row][c8];
        *(uint4*)(o_out + (size_t)(b * 64 + row) * 256 + cbase + c8) = v;
    }
}

// ---------------- MFMA attention for K=4 (NSP=16): block = 1 patch, wave = 1 head.
// One 16x16x32 MFMA for QK^T; PV via zero-padded (K=32, m>=16 zero) MFMAs.
// Waves fully independent after one weights barrier.
__global__ __launch_bounds__(256) void attn4_mfma_kernel(
    const ushort* __restrict__ qkv,  // [2048*16][512] bf16
    const ushort* __restrict__ wt,   // [9][256] bf16
    const float* __restrict__ pe_b,  // [256] fp32
    ushort* __restrict__ o_out)      // [2048*16][256] bf16
{
    constexpr float SCALE = 0.17677669529663687f;  // 32^-0.5
    __shared__ __attribute__((aligned(16))) ushort wsh[9][256];   // dwconv weights, all heads
    __shared__ float bsh[256];
    __shared__ __attribute__((aligned(16))) ushort Vt4[4][64][32]; // [wave][d][m swz], m>=16 zero
    __shared__ __attribute__((aligned(16))) ushort VP[4][16][64];  // V rows -> PE -> O (per wave)
    __shared__ __attribute__((aligned(16))) ushort Pm[4][16][32];  // P[n][m swz], m>=16 zero
    const int tid  = threadIdx.x;
    const int lane = tid & 63;
    const int w    = tid >> 6;       // wave = head
    const int b    = blockIdx.x;     // patch
    const int h    = w;
    const int cbase = h * 64;
    const int l15  = lane & 15, quad = lane >> 4;
    const ushort* base = qkv + (size_t)b * 16 * 512 + h * 128;

    // ---- cooperative stage of dwconv weights + bias (only cross-wave dependency)
    for (int i = tid; i < 9 * 32; i += 256) {
        int tap = i >> 5, c8 = (i & 31) * 8;
        *(uint4*)&wsh[tap][c8] = *(const uint4*)&wt[tap * 256 + c8];
    }
    bsh[tid] = pe_b[tid];
    __syncthreads();

    // ---- zero Vt4 (m>=16 rows must be 0 for the padded MFMA) and Pm
    {
        uint4 z = {0u, 0u, 0u, 0u};
#pragma unroll
        for (int t = 0; t < 4; ++t)
            *(uint4*)&Vt4[w][t * 16 + (lane >> 2)][(lane & 3) * 8] = z;
        *(uint4*)&Pm[w][lane >> 2][(lane & 3) * 8] = z;
    }

    // ---- stage V: lane -> (token m = lane&15, d-block = lane>>4)
    {
        const int m = lane & 15, dblk = lane >> 4;
        const ushort* vsrc = base + (size_t)m * 512 + 64 + dblk * 16;
        uint4 v0 = *(const uint4*)(vsrc);
        uint4 v1 = *(const uint4*)(vsrc + 8);
        *(uint4*)&VP[w][m][dblk * 16]     = v0;   // row-major copy (PE source)
        *(uint4*)&VP[w][m][dblk * 16 + 8] = v1;
        ushort us[16];
        *(uint4*)&us[0] = v0; *(uint4*)&us[8] = v1;
        const int mb = m >> 3, m7 = m & 7;
#pragma unroll
        for (int e = 0; e < 16; ++e) {
            int d = dblk * 16 + e;
            Vt4[w][d][((mb ^ (d & 3)) << 3) + m7] = us[e];  // d-major, col-swizzled
        }
    }

    // ---- QK^T: one 16x16x32 MFMA
    bf16x8 fq = *(const bf16x8*)(base + (size_t)l15 * 512 + quad * 8);
    bf16x8 fk = *(const bf16x8*)(base + (size_t)l15 * 512 + 32 + quad * 8);
    f32x4 z4 = {0.f, 0.f, 0.f, 0.f};
    f32x4 S = __builtin_amdgcn_mfma_f32_16x16x32_bf16(fq, fk, z4, 0, 0, 0);
    // lane holds S[n=quad*4+r][m=l15]

    // ---- softmax over m (across l15 within 16-lane group), wave-parallel
    float p[4];
#pragma unroll
    for (int r = 0; r < 4; ++r) {
        float v = S[r] * SCALE;
        float mx = v;
        mx = fmaxf(mx, __shfl_xor(mx, 1));
        mx = fmaxf(mx, __shfl_xor(mx, 2));
        mx = fmaxf(mx, __shfl_xor(mx, 4));
        mx = fmaxf(mx, __shfl_xor(mx, 8));
        float e = __expf(v - mx);
        float sum = e;
        sum += __shfl_xor(sum, 1);
        sum += __shfl_xor(sum, 2);
        sum += __shfl_xor(sum, 4);
        sum += __shfl_xor(sum, 8);
        p[r] = e / sum;
    }
    // ---- P -> Pm (swizzled cols; logical m>=16 stays zero)
#pragma unroll
    for (int r = 0; r < 4; ++r) {
        int n = quad * 4 + r;
        Pm[w][n][(((l15 >> 3) ^ (n & 3)) << 3) + (l15 & 7)] = f2bf(p[r]);
    }

    // ---- PE dwconv3x3 over V (from VP rows), 2 items/lane: (n=lane&15, ch, ch+4)
    float pe[2][8];
    const int n_ = lane & 15;
    const int pp0 = n_ >> 2, qq0 = n_ & 3;
#pragma unroll
    for (int it = 0; it < 2; ++it) {
        int ch = (lane >> 4) + it * 4;
#pragma unroll
        for (int e = 0; e < 8; ++e) pe[it][e] = bsh[cbase + ch * 8 + e];
    }
#pragma unroll
    for (int tap = 0; tap < 9; ++tap) {
        const int dp = tap / 3 - 1, dq = tap % 3 - 1;
        const int pp = pp0 + dp, qq = qq0 + dq;
        if (pp >= 0 && pp < 4 && qq >= 0 && qq < 4) {
            const int mm = pp * 4 + qq;
#pragma unroll
            for (int it = 0; it < 2; ++it) {
                int ch = (lane >> 4) + it * 4;
                uint4 wv4 = *(const uint4*)&wsh[tap][cbase + ch * 8];
                uint4 vv  = *(const uint4*)&VP[w][mm][ch * 8];
                unsigned uw[4] = {wv4.x, wv4.y, wv4.z, wv4.w};
                unsigned uv[4] = {vv.x, vv.y, vv.z, vv.w};
#pragma unroll
                for (int e2 = 0; e2 < 4; ++e2) {
                    float wlo = __uint_as_float(uw[e2] << 16);
                    float whi = __uint_as_float(uw[e2] & 0xFFFF0000u);
                    float vlo = __uint_as_float(uv[e2] << 16);
                    float vhi = __uint_as_float(uv[e2] & 0xFFFF0000u);
                    pe[it][2 * e2]     += wlo * vlo;
                    pe[it][2 * e2 + 1] += whi * vhi;
                }
            }
        }
    }
    // store PE into VP (all taps read before any store: same-wave program order)
#pragma unroll
    for (int it = 0; it < 2; ++it) {
        int ch = (lane >> 4) + it * 4;
        ushort pk[8];
#pragma unroll
        for (int e = 0; e < 8; ++e) pk[e] = f2bf(pe[it][e]);
        *(uint4*)&VP[w][n_][ch * 8] = *(const uint4*)pk;
    }

    // ---- O init from PE: O[n=quad*4+r][d=dt*16+l15]
    f32x4 O[4];
#pragma unroll
    for (int dt = 0; dt < 4; ++dt)
#pragma unroll
        for (int r = 0; r < 4; ++r)
            O[dt][r] = bf2f(VP[w][quad * 4 + r][dt * 16 + l15]);

    // ---- PV: 4 zero-padded 16x16x32 MFMAs
    bf16x8 fp = *(const bf16x8*)&Pm[w][l15][((quad ^ (l15 & 3)) << 3)];
#pragma unroll
    for (int dt = 0; dt < 4; ++dt) {
        bf16x8 fv = *(const bf16x8*)&Vt4[w][dt * 16 + l15][((quad ^ (l15 & 3)) << 3)];
        O[dt] = __builtin_amdgcn_mfma_f32_16x16x32_bf16(fp, fv, O[dt], 0, 0, 0);
    }

    // ---- O -> VP, then coalesced copy-out (16 rows x 128B)
#pragma unroll
    for (int dt = 0; dt < 4; ++dt)
#pragma unroll
        for (int r = 0; r < 4; ++r)
            VP[w][quad * 4 + r][dt * 16 + l15] = f2bf(O[dt][r]);

#pragma unroll
    for (int j = 0; j < 2; ++j) {
        int idx = j * 64 + lane;            // 0..127
        int row = idx >> 3, c8 = (idx & 7) * 8;
        uint4 v = *(const uint4*)&VP[w][row][c8];
        *(uint4*)(o_out + (size_t)(b * 16 + row) * 256 + cbase + c8) = v;
    }
}

// ---------------- final: out = (x + fold8(s8) + fold4(s4)) / 3
// v2: LDS-staged slabs (s8/s4 slices for (g,c2) are contiguous) -> coalesced HBM reads;
// scattered 2B fold reads hit LDS instead of HBM. float4 x/out.
__global__ __launch_bounds__(256) void final_kernel(
    const float* __restrict__ x,
    const ushort* __restrict__ s8,
    const ushort* __restrict__ s4,
    float* __restrict__ out)
{
    __shared__ __attribute__((aligned(16))) ushort l8[14400];  // [p][q][lh][lw]
    __shared__ __attribute__((aligned(16))) ushort l4[4096];   // [h&3][w&3][h>>2][w>>2]
    const int c2 = blockIdx.x & 255;
    const int g  = blockIdx.x >> 8;
    const int tid = threadIdx.x;
    const ushort* s8g = s8 + (size_t)g * (256 * 64 * 225) + (size_t)c2 * 14400;
    const ushort* s4g = s4 + (size_t)g * (256 * 16 * 256) + (size_t)c2 * 4096;
#pragma unroll
    for (int i = 0; i < 8; ++i) {
        int idx = i * 256 + tid;
        if (idx < 1800) *(uint4*)&l8[idx * 8] = *(const uint4*)&s8g[idx * 8];
    }
#pragma unroll
    for (int i = 0; i < 2; ++i) {
        int idx = i * 256 + tid;
        *(uint4*)&l4[idx * 8] = *(const uint4*)&s4g[idx * 8];
    }
    __syncthreads();
    const float third = 1.f / 3.f;
    const size_t gc_off = ((size_t)(g * 256 + c2)) * 4096;
#pragma unroll
    for (int it = 0; it < 4; ++it) {
        int pix0 = it * 1024 + tid * 4;         // 4 consecutive pixels, same h
        int h = pix0 >> 6, w0 = pix0 & 63;
        int lh_lo = (h >= 8) ? ((h - 4) >> 2) : 0, lh_hi = min(14, h >> 2);
        float4 xv = *(const float4*)(x + gc_off + pix0);
        float xa[4] = {xv.x, xv.y, xv.z, xv.w};
        float o4[4];
#pragma unroll
        for (int j = 0; j < 4; ++j) {
            int w = w0 + j;
            int lw_lo = (w >= 8) ? ((w - 4) >> 2) : 0, lw_hi = min(14, w >> 2);
            float v4 = bf2f(l4[(((h & 3) * 4 + (w & 3)) * 16 + (h >> 2)) * 16 + (w >> 2)]);
            float v8 = 0.f;
            for (int lh2 = lh_lo; lh2 <= lh_hi; ++lh2) {
                int p2 = h - lh2 * 4;
                for (int lw2 = lw_lo; lw2 <= lw_hi; ++lw2) {
                    int q2 = w - lw2 * 4;
                    v8 += bf2f(l8[((p2 * 8 + q2) * 15 + lh2) * 15 + lw2]);
                }
            }
            float inv = 1.f / (float)((lh_hi - lh_lo + 1) * (lw_hi - lw_lo + 1));
            o4[j] = (xa[j] + v8 * inv + v4) * third;
        }
        float4 ov = {o4[0], o4[1], o4[2], o4[3]};
        *(float4*)(out + gc_off + pix0) = ov;
    }
}

extern "C" void kernel_launch(void* const* d_in, const int* in_sizes, int n_in,
                              void* d_out, int out_size, void* d_ws, size_t ws_size,
                              hipStream_t stream)
{
    const float* x      = (const float*)d_in[0];
    const float* qkv_w  = (const float*)d_in[1];
    const float* qkv_b  = (const float*)d_in[2];
    const float* proj_w = (const float*)d_in[3];
    const float* proj_b = (const float*)d_in[4];
    const float* apw    = (const float*)d_in[5];
    const float* apb    = (const float*)d_in[6];
    const float* dpw    = (const float*)d_in[7];
    const float* dpb    = (const float*)d_in[8];
    float* out = (float*)d_out;

    // Workspace: s8 59 + s4 16.8 + y 29.5 + q 59 + w 0.4 + B(bf16) 17.3 = 182.1 MB
    const size_t S8_B = 8ull * 225 * 256 * 64 * 2;
    const size_t S4_B = 8ull * 256 * 256 * 16 * 2;
    const size_t Y_B  = 4ull * 14400 * 256 * 2;
    const size_t Q_B  = 4ull * 14400 * 512 * 2;
    const size_t W_B  = (512ull * 256 + 256ull * 256 + 9ull * 256) * 2;
    const size_t B_B  = 8ull * 65 * 65 * 256 * 2;
    if (ws_size < S8_B + S4_B + Y_B + Q_B + W_B + B_B) {
        hipMemsetAsync(d_out, 0x46, 4, stream);  // finite sentinel: ws too small
        return;
    }
    ushort* s8    = (ushort*)d_ws;
    ushort* s4    = s8 + S8_B / 2;
    ushort* ybuf  = s4 + S4_B / 2;
    ushort* qbuf  = ybuf + Y_B / 2;
    ushort* qw_bf = qbuf + Q_B / 2;
    ushort* pw_bf = qw_bf + 512 * 256;
    ushort* wt    = pw_bf + 256 * 256;
    ushort* Bbuf  = (ushort*)((char*)d_ws + S8_B + S4_B + Y_B + Q_B + W_B);

    f2bf_kernel<<<128, 256, 0, stream>>>(qkv_w, qw_bf);
    f2bf_kernel<<<64, 256, 0, stream>>>(proj_w, pw_bf);
    pe_prep_kernel<<<9, 256, 0, stream>>>(apw, wt);
    box_kernel<<<8 * 65, 256, 0, stream>>>(x, Bbuf);   // all 8 images, once

    // K=8 chain (L=15), two halves of 4 images: 4*14400 = 57600 rows = 450 tiles of 128
    for (int hf = 0; hf < 2; ++hf) {
        ushort* B_h = Bbuf + (size_t)hf * 4 * 65 * 65 * 256;
        ushort* s8_h = s8 + (size_t)hf * 4 * 225 * 256 * 64;
        pool_kernel<8, 15><<<4 * 225, 256, 0, stream>>>(B_h, dpw, dpb, ybuf);
        gemm_kernel<512, 0, 8, 15, 450><<<57 * 8 * 4, 256, 0, stream>>>(ybuf, qw_bf, qkv_b, qbuf);
        attn8_mfma_kernel<<<900 * 4, 128, 0, stream>>>(qbuf, wt, apb, ybuf);
        gemm_kernel<256, 1, 8, 15, 450><<<57 * 8 * 2, 256, 0, stream>>>(ybuf, pw_bf, proj_b, s8_h);
    }
    // K=4 chain (L=16), all 8 images: 8*4096 = 32768 rows = 256 tiles of 128
    pool_kernel<4, 16><<<8 * 256, 256, 0, stream>>>(Bbuf, dpw, dpb, ybuf);
    gemm_kernel<512, 0, 4, 16, 256><<<32 * 8 * 4, 256, 0, stream>>>(ybuf, qw_bf, qkv_b, qbuf);
    attn4_mfma_kernel<<<2048, 256, 0, stream>>>(qbuf, wt, apb, ybuf);
    gemm_kernel<256, 1, 4, 16, 256><<<32 * 8 * 2, 256, 0, stream>>>(ybuf, pw_bf, proj_b, s4);

    final_kernel<<<2048, 256, 0, stream>>>(x, s8, s4, out);
}

// Round 8
// 358.396 us; speedup vs baseline: 1.0901x; 1.0298x over previous
//
#include <hip/hip_runtime.h>
#include <hip/hip_bf16.h>

typedef __bf16 bf16x8 __attribute__((ext_vector_type(8)));
typedef float  f32x4  __attribute__((ext_vector_type(4)));

#define DEV static __device__ __forceinline__

DEV float bf2f(ushort u) { unsigned x = ((unsigned)u) << 16; return __uint_as_float(x); }
// native RNE via v_cvt_pk_bf16_f32 (bit-identical to manual round-to-nearest-even)
DEV ushort f2bf(float f) {
    __bf16 b = (__bf16)f;
    return __builtin_bit_cast(ushort, b);
}

typedef __attribute__((address_space(1))) const unsigned int gu32;
typedef __attribute__((address_space(3))) unsigned int lu32;
DEV void gload16(const ushort* g, ushort* l) {
    __builtin_amdgcn_global_load_lds((gu32*)g, (lu32*)l, 16, 0, 0);
}

// ---------------- fp32 -> bf16 weight conversion (one-time, tiny) ----------------
__global__ __launch_bounds__(256) void f2bf_kernel(
    const float* __restrict__ src, ushort* __restrict__ dst)
{
    int i = (blockIdx.x * 256 + threadIdx.x) * 4;
    float4 v = *(const float4*)(src + i);
    ushort4 o;
    o.x = f2bf(v.x); o.y = f2bf(v.y); o.z = f2bf(v.z); o.w = f2bf(v.w);
    *(ushort4*)(dst + i) = o;
}

// ---------------- attn-PE weight transpose: [256][9] fp32 -> [9][256] bf16 ----------------
__global__ __launch_bounds__(256) void pe_prep_kernel(
    const float* __restrict__ apw, ushort* __restrict__ wt)
{
    int i = blockIdx.x * 256 + threadIdx.x;
    if (i < 9 * 256) {
        int tap = i >> 8, c = i & 255;
        wt[i] = f2bf(apw[c * 9 + tap]);
    }
}

// ---------------- box filter: B[g][br][bc][256] bf16, br,bc in [0,65) ----------------
__global__ __launch_bounds__(256) void box_kernel(
    const float* __restrict__ x,   // [8][256][64][64] fp32
    ushort* __restrict__ B)        // [8][65][65][256] bf16
{
    int br = blockIdx.x % 65; int g = blockIdx.x / 65;
    const float* xg = x + (size_t)g * 256 * 4096;
    ushort* Bg = B + (size_t)g * 65 * 65 * 256;
    const int r0 = max(br - 1, 0) * 64;
    const int r1 = min(br, 63) * 64;
    __shared__ float s[128][65];
    const int wl = threadIdx.x & 63, cq = threadIdx.x >> 6;   // load mapping
    const int c2 = threadIdx.x & 127, bh = threadIdx.x >> 7;  // store mapping
    for (int half = 0; half < 2; ++half) {
#pragma unroll 4
        for (int it = 0; it < 32; ++it) {
            int cl_ = it * 4 + cq;
            const float* xp = xg + (size_t)(half * 128 + cl_) * 4096;
            s[cl_][wl] = xp[r0 + wl] + xp[r1 + wl];
        }
        __syncthreads();
        for (int bc = bh; bc < 65; bc += 2) {
            float v = 0.25f * (s[c2][max(bc - 1, 0)] + s[c2][min(bc, 63)]);
            Bg[((size_t)br * 65 + bc) * 256 + half * 128 + c2] = f2bf(v);
        }
        __syncthreads();
    }
}

// ---------------- pool gather + depthwise 3x3 + residual ----------------
template<int K, int L>
__global__ __launch_bounds__(256) void pool_kernel(
    const ushort* __restrict__ B,   // [8][65][65][256] bf16
    const float* __restrict__ w9,   // [256][9] fp32
    const float* __restrict__ bias, // [256] fp32
    ushort* __restrict__ y)         // bf16 out
{
    constexpr int HF = K / 2;
    const int pk = blockIdx.x;
    const int lw = pk % L; int t = pk / L; const int lh = t % L; const int g = t / L;
    const int c = threadIdx.x;
    const ushort* Bg = B + (size_t)g * 65 * 65 * 256 + c;
    float pool[K][K];
#pragma unroll
    for (int p = 0; p < K; ++p) {
        const int br = lh * 4 + p + (p >= HF ? 1 : 0);
#pragma unroll
        for (int q = 0; q < K; ++q) {
            const int bc = lw * 4 + q + (q >= HF ? 1 : 0);
            pool[p][q] = bf2f(Bg[((size_t)br * 65 + bc) * 256]);
        }
    }
    float wv[9];
#pragma unroll
    for (int i = 0; i < 9; ++i) wv[i] = w9[c * 9 + i];
    const float bv = bias[c];
    ushort* yp = y + (size_t)pk * (K * K) * 256 + c;
#pragma unroll
    for (int p = 0; p < K; ++p) {
#pragma unroll
        for (int q = 0; q < K; ++q) {
            float a = pool[p][q] + bv;   // residual + conv bias
#pragma unroll
            for (int dp = -1; dp <= 1; ++dp) {
#pragma unroll
                for (int dq = -1; dq <= 1; ++dq) {
                    int pp = p + dp, qq = q + dq;
                    if (pp >= 0 && pp < K && qq >= 0 && qq < K)
                        a += wv[(dp + 1) * 3 + (dq + 1)] * pool[pp][qq];
                }
            }
            yp[(p * K + q) * 256] = f2bf(a);
        }
    }
}

// ---------------- GEMM 128x128 tiles (m97 structure): global_load_lds staging,
// linear LDS dest + inverse-swizzled global source + swizzled ds_read_b128.
template<int OC, int EPI, int K, int L, int RT>
__global__ __launch_bounds__(256) void gemm_kernel(
    const ushort* __restrict__ act,  // [rows][256] bf16
    const ushort* __restrict__ w,    // [OC][256]  bf16
    const float* __restrict__ bias,  // [OC] fp32
    ushort* __restrict__ out_bf)
{
    __shared__ __attribute__((aligned(16))) ushort As[128][32];
    __shared__ __attribute__((aligned(16))) ushort Ws[128][32];
    constexpr int NT = OC / 128;
    const int id  = blockIdx.x;
    const int xc  = id & 7;                 // XCD-aware row-tile swizzle
    const int ctb = (id >> 3) % NT;
    const int tt  = id / (8 * NT);
    const int rowt = tt * 8 + xc;
    if (rowt >= RT) return;
    const int tid  = threadIdx.x;
    const int n0   = rowt * 128;
    const int ch0  = ctb * 128;
    const int wv   = tid >> 6, lane = tid & 63;
    const int l15  = lane & 15, quad = lane >> 4;
    const int wm   = wv >> 1, wn = wv & 1;   // 2x2 wave grid, 64x64 out per wave

    const int qlog = (lane & 3) ^ ((lane >> 3) & 3);
    const size_t soff = (size_t)(lane >> 2) * 256 + (size_t)qlog * 8;
    const ushort* aS0 = act + ((size_t)n0 + wv * 32) * 256 + soff;
    const ushort* wS0 = w   + ((size_t)ch0 + wv * 32) * 256 + soff;
    const ushort* aS1 = aS0 + 16 * 256;
    const ushort* wS1 = wS0 + 16 * 256;
    ushort* aD0 = &As[wv * 32][0];           // wave-uniform LDS bases
    ushort* wD0 = &Ws[wv * 32][0];
    ushort* aD1 = aD0 + 16 * 32;
    ushort* wD1 = wD0 + 16 * 32;

    const int rcol = (quad ^ ((l15 >> 1) & 3)) * 8;  // swizzled read column
    f32x4 acc[4][4] = {};
    for (int k0 = 0; k0 < 256; k0 += 32) {
        gload16(aS0 + k0, aD0);
        gload16(aS1 + k0, aD1);
        gload16(wS0 + k0, wD0);
        gload16(wS1 + k0, wD1);
        __syncthreads();                     // drains vmcnt before barrier
        bf16x8 af[4], bw[4];
#pragma unroll
        for (int t = 0; t < 4; ++t) {
            af[t] = *(const bf16x8*)&As[wm * 64 + t * 16 + l15][rcol];
            bw[t] = *(const bf16x8*)&Ws[wn * 64 + t * 16 + l15][rcol];
        }
#pragma unroll
        for (int mt = 0; mt < 4; ++mt)
#pragma unroll
            for (int nt = 0; nt < 4; ++nt)
                acc[mt][nt] = __builtin_amdgcn_mfma_f32_16x16x32_bf16(af[mt], bw[nt], acc[mt][nt], 0, 0, 0);
        __syncthreads();
    }

    float bv[4];
#pragma unroll
    for (int nt = 0; nt < 4; ++nt) bv[nt] = bias[ch0 + wn * 64 + nt * 16 + l15];
#pragma unroll
    for (int mt = 0; mt < 4; ++mt) {
#pragma unroll
        for (int r = 0; r < 4; ++r) {
            const int n = n0 + wm * 64 + mt * 16 + quad * 4 + r;
            if (EPI == 0) {
                ushort* dst = out_bf + (size_t)n * OC + ch0 + wn * 64;
#pragma unroll
                for (int nt = 0; nt < 4; ++nt)
                    dst[nt * 16 + l15] = f2bf(acc[mt][nt][r] + bv[nt]);
            } else {
                constexpr int K2 = K * K;
                constexpr int LL = L * L;
                const int b_g   = n >> (K == 8 ? 6 : 4);
                const int pq    = n & (K2 - 1);
                const int gl    = b_g / LL;
                const int b_loc = b_g - gl * LL;
                const size_t base = (size_t)gl * (256 * K2 * LL) + (size_t)b_loc * 256 * K2 + pq;
#pragma unroll
                for (int nt = 0; nt < 4; ++nt) {
                    const int ch = ch0 + wn * 64 + nt * 16 + l15;
                    out_bf[base + (size_t)ch * K2] = f2bf(acc[mt][nt][r] + bv[nt]);
                }
            }
        }
    }
}

// ---------------- MFMA attention for K=8 (NSP=64): block = 1 patch x 1 head, 128 thr.
// v3 + native cvt_pk bf16 packs + setprio around MFMA clusters.
__global__ __launch_bounds__(128, 4) void attn8_mfma_kernel(
    const ushort* __restrict__ qkv,  // [patches*64][512] bf16
    const ushort* __restrict__ wt,   // [9][256] bf16 (transposed attn-PE weights)
    const float* __restrict__ pe_b,  // [256] fp32
    ushort* __restrict__ o_out)      // [patches*64][256] bf16
{
    constexpr float SCALE = 0.17677669529663687f;  // 32^-0.5
    __shared__ __attribute__((aligned(16))) ushort PB[64][72];  // PE^T[d][n] -> P[n][m] -> O[n][d]
    __shared__ __attribute__((aligned(16))) ushort Vt[64][72];  // V^T (d-major)
    __shared__ __attribute__((aligned(16))) ushort wsh[9][64];  // dwconv w for this head
    __shared__ float bsh[64];
    const int tid  = threadIdx.x;
    const int lane = tid & 63;
    const int ww   = tid >> 6;           // wave 0/1
    const int b    = blockIdx.x >> 2;    // patch
    const int h    = blockIdx.x & 3;     // head
    const int cbase = h * 64;
    const int l15  = lane & 15, quad = lane >> 4;
    const ushort* base = qkv + (size_t)b * 64 * 512 + h * 128;

    // ---- per-wave stage of dwconv weights + bias (own 32-channel half; intra-wave use only)
    if (lane < 36) {
        int tap = lane >> 2, c8 = (lane & 3) * 8;
        *(uint4*)&wsh[tap][ww * 32 + c8] = *(const uint4*)&wt[tap * 256 + cbase + ww * 32 + c8];
    }
    if (lane < 32) bsh[ww * 32 + lane] = pe_b[cbase + ww * 32 + lane];

    // ---- stage V^T: wave ww owns d rows [ww*32, ww*32+32), token m = lane
    {
        const int m = lane;
        const ushort* vsrc = base + (size_t)m * 512 + 64 + ww * 32;
        const int d0 = ww * 32;
#pragma unroll
        for (int t = 0; t < 4; ++t) {
            uint4 vv = *(const uint4*)(vsrc + t * 8);
            unsigned u[4] = {vv.x, vv.y, vv.z, vv.w};
#pragma unroll
            for (int e = 0; e < 4; ++e) {
                Vt[d0 + t * 8 + e * 2][m]     = (ushort)(u[e] & 0xFFFF);
                Vt[d0 + t * 8 + e * 2 + 1][m] = (ushort)(u[e] >> 16);
            }
        }
    }

    // ---- Q fragments + QK^T (registers/global only)
    bf16x8 fq[2];
#pragma unroll
    for (int s = 0; s < 2; ++s) {
        int n = (ww + 2 * s) * 16 + l15;
        fq[s] = *(const bf16x8*)(base + (size_t)n * 512 + quad * 8);
    }
    f32x4 S[2][4];
    __builtin_amdgcn_s_setprio(1);
#pragma unroll
    for (int mt = 0; mt < 4; ++mt) {
        int m = mt * 16 + l15;
        bf16x8 fk = *(const bf16x8*)(base + (size_t)m * 512 + 32 + quad * 8);
#pragma unroll
        for (int s = 0; s < 2; ++s) {
            f32x4 z = {0.f, 0.f, 0.f, 0.f};
            S[s][mt] = __builtin_amdgcn_mfma_f32_16x16x32_bf16(fq[s], fk, z, 0, 0, 0);
        }
    }
    __builtin_amdgcn_s_setprio(0);

    // ---- PE dwconv, channel-per-lane: thread -> (d = ww*32+(lane&31), rows p)
    // Reads own wave's Vt rows (intra-wave in-order LDS: no barrier needed).
    {
        const int d   = ww * 32 + (lane & 31);
        const int pb4 = (lane >> 5) * 4;
        float wreg[9];
#pragma unroll
        for (int i = 0; i < 9; ++i) wreg[i] = bf2f(wsh[i][d]);
        const float bias0 = bsh[d];
#pragma unroll
        for (int it = 0; it < 4; ++it) {
            const int p = pb4 + it;
            float pe[8];
#pragma unroll
            for (int q = 0; q < 8; ++q) pe[q] = bias0;
#pragma unroll
            for (int dpi = 0; dpi < 3; ++dpi) {
                const int pp = p + dpi - 1;
                if (pp >= 0 && pp < 8) {
                    bf16x8 v8 = *(const bf16x8*)&Vt[d][pp * 8];
                    float v[8];
#pragma unroll
                    for (int e = 0; e < 8; ++e) v[e] = (float)v8[e];
                    const float w0 = wreg[dpi * 3], w1 = wreg[dpi * 3 + 1], w2 = wreg[dpi * 3 + 2];
                    pe[0] += w1 * v[0] + w2 * v[1];
#pragma unroll
                    for (int q = 1; q < 7; ++q) pe[q] += w0 * v[q - 1] + w1 * v[q] + w2 * v[q + 1];
                    pe[7] += w0 * v[6] + w1 * v[7];
                }
            }
            ushort pk[8];
#pragma unroll
            for (int e = 0; e < 8; ++e) pk[e] = f2bf(pe[e]);
            *(uint4*)&PB[d][p * 8] = *(const uint4*)pk;   // PE^T: row d, tokens p*8..+8
        }
    }
    __syncthreads();   // barrier 1: Vt + PE^T visible to both waves

    // ---- O init from PE^T: O[s][dt][r] = PE[n][d], b64 reads (4 consecutive n)
    f32x4 O[2][4];
#pragma unroll
    for (int s = 0; s < 2; ++s)
#pragma unroll
        for (int dt = 0; dt < 4; ++dt) {
            ushort4 t4 = *(const ushort4*)&PB[dt * 16 + l15][(ww + 2 * s) * 16 + quad * 4];
            O[s][dt][0] = bf2f(t4.x);
            O[s][dt][1] = bf2f(t4.y);
            O[s][dt][2] = bf2f(t4.z);
            O[s][dt][3] = bf2f(t4.w);
        }

    // ---- softmax (wave-parallel, registers)
#pragma unroll
    for (int s = 0; s < 2; ++s) {
#pragma unroll
        for (int r = 0; r < 4; ++r) {
            float mx = -1e30f;
#pragma unroll
            for (int mt = 0; mt < 4; ++mt) { S[s][mt][r] *= SCALE; mx = fmaxf(mx, S[s][mt][r]); }
            mx = fmaxf(mx, __shfl_xor(mx, 1));
            mx = fmaxf(mx, __shfl_xor(mx, 2));
            mx = fmaxf(mx, __shfl_xor(mx, 4));
            mx = fmaxf(mx, __shfl_xor(mx, 8));
            float sum = 0.f;
#pragma unroll
            for (int mt = 0; mt < 4; ++mt) { float e = __expf(S[s][mt][r] - mx); S[s][mt][r] = e; sum += e; }
            sum += __shfl_xor(sum, 1);
            sum += __shfl_xor(sum, 2);
            sum += __shfl_xor(sum, 4);
            sum += __shfl_xor(sum, 8);
            float inv = 1.f / sum;
#pragma unroll
            for (int mt = 0; mt < 4; ++mt) S[s][mt][r] *= inv;
        }
    }
    __syncthreads();   // barrier 2: all PE^T reads complete before P overwrites PB

    // ---- P -> PB n-major. Wave ww writes only rows {ww*16..+16, (ww+2)*16..+16}:
    // disjoint per wave; PV below reads only own-wave rows -> no barrier needed.
#pragma unroll
    for (int s = 0; s < 2; ++s)
#pragma unroll
        for (int r = 0; r < 4; ++r) {
            int n = (ww + 2 * s) * 16 + quad * 4 + r;
#pragma unroll
            for (int mt = 0; mt < 4; ++mt)
                PB[n][mt * 16 + l15] = f2bf(S[s][mt][r]);
        }

    // ---- PV (fp from own-wave P rows; fv from Vt, unchanged since barrier 1)
#pragma unroll
    for (int ks = 0; ks < 2; ++ks) {
        bf16x8 fp[2], fv[4];
#pragma unroll
        for (int s = 0; s < 2; ++s)
            fp[s] = *(const bf16x8*)&PB[(ww + 2 * s) * 16 + l15][ks * 32 + quad * 8];
#pragma unroll
        for (int dt = 0; dt < 4; ++dt)
            fv[dt] = *(const bf16x8*)&Vt[dt * 16 + l15][ks * 32 + quad * 8];
        __builtin_amdgcn_s_setprio(1);
#pragma unroll
        for (int s = 0; s < 2; ++s)
#pragma unroll
            for (int dt = 0; dt < 4; ++dt)
                O[s][dt] = __builtin_amdgcn_mfma_f32_16x16x32_bf16(fp[s], fv[dt], O[s][dt], 0, 0, 0);
        __builtin_amdgcn_s_setprio(0);
    }

    // ---- O -> own-wave PB rows, then per-wave coalesced copy-out (intra-wave only)
#pragma unroll
    for (int s = 0; s < 2; ++s)
#pragma unroll
        for (int r = 0; r < 4; ++r) {
            int n = (ww + 2 * s) * 16 + quad * 4 + r;
#pragma unroll
            for (int dt = 0; dt < 4; ++dt)
                PB[n][dt * 16 + l15] = f2bf(O[s][dt][r]);
        }
#pragma unroll
    for (int it = 0; it < 4; ++it) {
        int cidx = it * 64 + lane;               // 256 chunk-copies per wave
        int rl = cidx >> 3, c8 = (cidx & 7) * 8;
        int row = ww * 16 + (rl & 15) + (rl >> 4) * 32;  // own-wave rows only
        uint4 v = *(const uint4*)&PB[row][c8];
        *(uint4*)(o_out + (size_t)(b * 64 + row) * 256 + cbase + c8) = v;
    }
}

// ---------------- MFMA attention for K=4 (NSP=16): block = 1 patch, wave = 1 head.
// One 16x16x32 MFMA for QK^T; PV via zero-padded (K=32, m>=16 zero) MFMAs.
// Waves fully independent after one weights barrier.
__global__ __launch_bounds__(256) void attn4_mfma_kernel(
    const ushort* __restrict__ qkv,  // [2048*16][512] bf16
    const ushort* __restrict__ wt,   // [9][256] bf16
    const float* __restrict__ pe_b,  // [256] fp32
    ushort* __restrict__ o_out)      // [2048*16][256] bf16
{
    constexpr float SCALE = 0.17677669529663687f;  // 32^-0.5
    __shared__ __attribute__((aligned(16))) ushort wsh[9][256];   // dwconv weights, all heads
    __shared__ float bsh[256];
    __shared__ __attribute__((aligned(16))) ushort Vt4[4][64][32]; // [wave][d][m swz], m>=16 zero
    __shared__ __attribute__((aligned(16))) ushort VP[4][16][64];  // V rows -> PE -> O (per wave)
    __shared__ __attribute__((aligned(16))) ushort Pm[4][16][32];  // P[n][m swz], m>=16 zero
    const int tid  = threadIdx.x;
    const int lane = tid & 63;
    const int w    = tid >> 6;       // wave = head
    const int b    = blockIdx.x;     // patch
    const int h    = w;
    const int cbase = h * 64;
    const int l15  = lane & 15, quad = lane >> 4;
    const ushort* base = qkv + (size_t)b * 16 * 512 + h * 128;

    // ---- cooperative stage of dwconv weights + bias (only cross-wave dependency)
    for (int i = tid; i < 9 * 32; i += 256) {
        int tap = i >> 5, c8 = (i & 31) * 8;
        *(uint4*)&wsh[tap][c8] = *(const uint4*)&wt[tap * 256 + c8];
    }
    bsh[tid] = pe_b[tid];
    __syncthreads();

    // ---- zero Vt4 (m>=16 rows must be 0 for the padded MFMA) and Pm
    {
        uint4 z = {0u, 0u, 0u, 0u};
#pragma unroll
        for (int t = 0; t < 4; ++t)
            *(uint4*)&Vt4[w][t * 16 + (lane >> 2)][(lane & 3) * 8] = z;
        *(uint4*)&Pm[w][lane >> 2][(lane & 3) * 8] = z;
    }

    // ---- stage V: lane -> (token m = lane&15, d-block = lane>>4)
    {
        const int m = lane & 15, dblk = lane >> 4;
        const ushort* vsrc = base + (size_t)m * 512 + 64 + dblk * 16;
        uint4 v0 = *(const uint4*)(vsrc);
        uint4 v1 = *(const uint4*)(vsrc + 8);
        *(uint4*)&VP[w][m][dblk * 16]     = v0;   // row-major copy (PE source)
        *(uint4*)&VP[w][m][dblk * 16 + 8] = v1;
        ushort us[16];
        *(uint4*)&us[0] = v0; *(uint4*)&us[8] = v1;
        const int mb = m >> 3, m7 = m & 7;
#pragma unroll
        for (int e = 0; e < 16; ++e) {
            int d = dblk * 16 + e;
            Vt4[w][d][((mb ^ (d & 3)) << 3) + m7] = us[e];  // d-major, col-swizzled
        }
    }

    // ---- QK^T: one 16x16x32 MFMA
    bf16x8 fq = *(const bf16x8*)(base + (size_t)l15 * 512 + quad * 8);
    bf16x8 fk = *(const bf16x8*)(base + (size_t)l15 * 512 + 32 + quad * 8);
    f32x4 z4 = {0.f, 0.f, 0.f, 0.f};
    f32x4 S = __builtin_amdgcn_mfma_f32_16x16x32_bf16(fq, fk, z4, 0, 0, 0);
    // lane holds S[n=quad*4+r][m=l15]

    // ---- softmax over m (across l15 within 16-lane group), wave-parallel
    float p[4];
#pragma unroll
    for (int r = 0; r < 4; ++r) {
        float v = S[r] * SCALE;
        float mx = v;
        mx = fmaxf(mx, __shfl_xor(mx, 1));
        mx = fmaxf(mx, __shfl_xor(mx, 2));
        mx = fmaxf(mx, __shfl_xor(mx, 4));
        mx = fmaxf(mx, __shfl_xor(mx, 8));
        float e = __expf(v - mx);
        float sum = e;
        sum += __shfl_xor(sum, 1);
        sum += __shfl_xor(sum, 2);
        sum += __shfl_xor(sum, 4);
        sum += __shfl_xor(sum, 8);
        p[r] = e / sum;
    }
    // ---- P -> Pm (swizzled cols; logical m>=16 stays zero)
#pragma unroll
    for (int r = 0; r < 4; ++r) {
        int n = quad * 4 + r;
        Pm[w][n][(((l15 >> 3) ^ (n & 3)) << 3) + (l15 & 7)] = f2bf(p[r]);
    }

    // ---- PE dwconv3x3 over V (from VP rows), 2 items/lane: (n=lane&15, ch, ch+4)
    float pe[2][8];
    const int n_ = lane & 15;
    const int pp0 = n_ >> 2, qq0 = n_ & 3;
#pragma unroll
    for (int it = 0; it < 2; ++it) {
        int ch = (lane >> 4) + it * 4;
#pragma unroll
        for (int e = 0; e < 8; ++e) pe[it][e] = bsh[cbase + ch * 8 + e];
    }
#pragma unroll
    for (int tap = 0; tap < 9; ++tap) {
        const int dp = tap / 3 - 1, dq = tap % 3 - 1;
        const int pp = pp0 + dp, qq = qq0 + dq;
        if (pp >= 0 && pp < 4 && qq >= 0 && qq < 4) {
            const int mm = pp * 4 + qq;
#pragma unroll
            for (int it = 0; it < 2; ++it) {
                int ch = (lane >> 4) + it * 4;
                uint4 wv4 = *(const uint4*)&wsh[tap][cbase + ch * 8];
                uint4 vv  = *(const uint4*)&VP[w][mm][ch * 8];
                unsigned uw[4] = {wv4.x, wv4.y, wv4.z, wv4.w};
                unsigned uv[4] = {vv.x, vv.y, vv.z, vv.w};
#pragma unroll
                for (int e2 = 0; e2 < 4; ++e2) {
                    float wlo = __uint_as_float(uw[e2] << 16);
                    float whi = __uint_as_float(uw[e2] & 0xFFFF0000u);
                    float vlo = __uint_as_float(uv[e2] << 16);
                    float vhi = __uint_as_float(uv[e2] & 0xFFFF0000u);
                    pe[it][2 * e2]     += wlo * vlo;
                    pe[it][2 * e2 + 1] += whi * vhi;
                }
            }
        }
    }
    // store PE into VP (all taps read before any store: same-wave program order)
#pragma unroll
    for (int it = 0; it < 2; ++it) {
        int ch = (lane >> 4) + it * 4;
        ushort pk[8];
#pragma unroll
        for (int e = 0; e < 8; ++e) pk[e] = f2bf(pe[it][e]);
        *(uint4*)&VP[w][n_][ch * 8] = *(const uint4*)pk;
    }

    // ---- O init from PE: O[n=quad*4+r][d=dt*16+l15]
    f32x4 O[4];
#pragma unroll
    for (int dt = 0; dt < 4; ++dt)
#pragma unroll
        for (int r = 0; r < 4; ++r)
            O[dt][r] = bf2f(VP[w][quad * 4 + r][dt * 16 + l15]);

    // ---- PV: 4 zero-padded 16x16x32 MFMAs
    bf16x8 fp = *(const bf16x8*)&Pm[w][l15][((quad ^ (l15 & 3)) << 3)];
    __builtin_amdgcn_s_setprio(1);
#pragma unroll
    for (int dt = 0; dt < 4; ++dt) {
        bf16x8 fv = *(const bf16x8*)&Vt4[w][dt * 16 + l15][((quad ^ (l15 & 3)) << 3)];
        O[dt] = __builtin_amdgcn_mfma_f32_16x16x32_bf16(fp, fv, O[dt], 0, 0, 0);
    }
    __builtin_amdgcn_s_setprio(0);

    // ---- O -> VP, then coalesced copy-out (16 rows x 128B)
#pragma unroll
    for (int dt = 0; dt < 4; ++dt)
#pragma unroll
        for (int r = 0; r < 4; ++r)
            VP[w][quad * 4 + r][dt * 16 + l15] = f2bf(O[dt][r]);

#pragma unroll
    for (int j = 0; j < 2; ++j) {
        int idx = j * 64 + lane;            // 0..127
        int row = idx >> 3, c8 = (idx & 7) * 8;
        uint4 v = *(const uint4*)&VP[w][row][c8];
        *(uint4*)(o_out + (size_t)(b * 16 + row) * 256 + cbase + c8) = v;
    }
}

// ---------------- final: out = (x + fold8(s8) + fold4(s4)) / 3
// v2: LDS-staged slabs (s8/s4 slices for (g,c2) are contiguous) -> coalesced HBM reads;
// scattered 2B fold reads hit LDS instead of HBM. float4 x/out.
__global__ __launch_bounds__(256) void final_kernel(
    const float* __restrict__ x,
    const ushort* __restrict__ s8,
    const ushort* __restrict__ s4,
    float* __restrict__ out)
{
    __shared__ __attribute__((aligned(16))) ushort l8[14400];  // [p][q][lh][lw]
    __shared__ __attribute__((aligned(16))) ushort l4[4096];   // [h&3][w&3][h>>2][w>>2]
    const int c2 = blockIdx.x & 255;
    const int g  = blockIdx.x >> 8;
    const int tid = threadIdx.x;
    const ushort* s8g = s8 + (size_t)g * (256 * 64 * 225) + (size_t)c2 * 14400;
    const ushort* s4g = s4 + (size_t)g * (256 * 16 * 256) + (size_t)c2 * 4096;
#pragma unroll
    for (int i = 0; i < 8; ++i) {
        int idx = i * 256 + tid;
        if (idx < 1800) *(uint4*)&l8[idx * 8] = *(const uint4*)&s8g[idx * 8];
    }
#pragma unroll
    for (int i = 0; i < 2; ++i) {
        int idx = i * 256 + tid;
        *(uint4*)&l4[idx * 8] = *(const uint4*)&s4g[idx * 8];
    }
    __syncthreads();
    const float third = 1.f / 3.f;
    const size_t gc_off = ((size_t)(g * 256 + c2)) * 4096;
#pragma unroll
    for (int it = 0; it < 4; ++it) {
        int pix0 = it * 1024 + tid * 4;         // 4 consecutive pixels, same h
        int h = pix0 >> 6, w0 = pix0 & 63;
        int lh_lo = (h >= 8) ? ((h - 4) >> 2) : 0, lh_hi = min(14, h >> 2);
        float4 xv = *(const float4*)(x + gc_off + pix0);
        float xa[4] = {xv.x, xv.y, xv.z, xv.w};
        float o4[4];
#pragma unroll
        for (int j = 0; j < 4; ++j) {
            int w = w0 + j;
            int lw_lo = (w >= 8) ? ((w - 4) >> 2) : 0, lw_hi = min(14, w >> 2);
            float v4 = bf2f(l4[(((h & 3) * 4 + (w & 3)) * 16 + (h >> 2)) * 16 + (w >> 2)]);
            float v8 = 0.f;
            for (int lh2 = lh_lo; lh2 <= lh_hi; ++lh2) {
                int p2 = h - lh2 * 4;
                for (int lw2 = lw_lo; lw2 <= lw_hi; ++lw2) {
                    int q2 = w - lw2 * 4;
                    v8 += bf2f(l8[((p2 * 8 + q2) * 15 + lh2) * 15 + lw2]);
                }
            }
            float inv = 1.f / (float)((lh_hi - lh_lo + 1) * (lw_hi - lw_lo + 1));
            o4[j] = (xa[j] + v8 * inv + v4) * third;
        }
        float4 ov = {o4[0], o4[1], o4[2], o4[3]};
        *(float4*)(out + gc_off + pix0) = ov;
    }
}

extern "C" void kernel_launch(void* const* d_in, const int* in_sizes, int n_in,
                              void* d_out, int out_size, void* d_ws, size_t ws_size,
                              hipStream_t stream)
{
    const float* x      = (const float*)d_in[0];
    const float* qkv_w  = (const float*)d_in[1];
    const float* qkv_b  = (const float*)d_in[2];
    const float* proj_w = (const float*)d_in[3];
    const float* proj_b = (const float*)d_in[4];
    const float* apw    = (const float*)d_in[5];
    const float* apb    = (const float*)d_in[6];
    const float* dpw    = (const float*)d_in[7];
    const float* dpb    = (const float*)d_in[8];
    float* out = (float*)d_out;

    // Workspace: s8 59 + s4 16.8 + y 29.5 + q 59 + w 0.4 + B(bf16) 17.3 = 182.1 MB
    const size_t S8_B = 8ull * 225 * 256 * 64 * 2;
    const size_t S4_B = 8ull * 256 * 256 * 16 * 2;
    const size_t Y_B  = 4ull * 14400 * 256 * 2;
    const size_t Q_B  = 4ull * 14400 * 512 * 2;
    const size_t W_B  = (512ull * 256 + 256ull * 256 + 9ull * 256) * 2;
    const size_t B_B  = 8ull * 65 * 65 * 256 * 2;
    if (ws_size < S8_B + S4_B + Y_B + Q_B + W_B + B_B) {
        hipMemsetAsync(d_out, 0x46, 4, stream);  // finite sentinel: ws too small
        return;
    }
    ushort* s8    = (ushort*)d_ws;
    ushort* s4    = s8 + S8_B / 2;
    ushort* ybuf  = s4 + S4_B / 2;
    ushort* qbuf  = ybuf + Y_B / 2;
    ushort* qw_bf = qbuf + Q_B / 2;
    ushort* pw_bf = qw_bf + 512 * 256;
    ushort* wt    = pw_bf + 256 * 256;
    ushort* Bbuf  = (ushort*)((char*)d_ws + S8_B + S4_B + Y_B + Q_B + W_B);

    f2bf_kernel<<<128, 256, 0, stream>>>(qkv_w, qw_bf);
    f2bf_kernel<<<64, 256, 0, stream>>>(proj_w, pw_bf);
    pe_prep_kernel<<<9, 256, 0, stream>>>(apw, wt);
    box_kernel<<<8 * 65, 256, 0, stream>>>(x, Bbuf);   // all 8 images, once

    // K=8 chain (L=15), two halves of 4 images: 4*14400 = 57600 rows = 450 tiles of 128
    for (int hf = 0; hf < 2; ++hf) {
        ushort* B_h = Bbuf + (size_t)hf * 4 * 65 * 65 * 256;
        ushort* s8_h = s8 + (size_t)hf * 4 * 225 * 256 * 64;
        pool_kernel<8, 15><<<4 * 225, 256, 0, stream>>>(B_h, dpw, dpb, ybuf);
        gemm_kernel<512, 0, 8, 15, 450><<<57 * 8 * 4, 256, 0, stream>>>(ybuf, qw_bf, qkv_b, qbuf);
        attn8_mfma_kernel<<<900 * 4, 128, 0, stream>>>(qbuf, wt, apb, ybuf);
        gemm_kernel<256, 1, 8, 15, 450><<<57 * 8 * 2, 256, 0, stream>>>(ybuf, pw_bf, proj_b, s8_h);
    }
    // K=4 chain (L=16), all 8 images: 8*4096 = 32768 rows = 256 tiles of 128
    pool_kernel<4, 16><<<8 * 256, 256, 0, stream>>>(Bbuf, dpw, dpb, ybuf);
    gemm_kernel<512, 0, 4, 16, 256><<<32 * 8 * 4, 256, 0, stream>>>(ybuf, qw_bf, qkv_b, qbuf);
    attn4_mfma_kernel<<<2048, 256, 0, stream>>>(qbuf, wt, apb, ybuf);
    gemm_kernel<256, 1, 4, 16, 256><<<32 * 8 * 2, 256, 0, stream>>>(ybuf, pw_bf, proj_b, s4);

    final_kernel<<<2048, 256, 0, stream>>>(x, s8, s4, out);
}